// Round 6
// baseline (196.093 us; speedup 1.0000x reference)
//
#include <hip/hip_runtime.h>
#include <hip/hip_bf16.h>

// MPNScoreModule: B=8 graphs, N=64 nodes, E=256 edges, L=128, S=2 steps.
// Round 6: main kernel byte-identical to round 5 (proven, 84.6 us).
// Prep rewritten: encoder GEMMs (ee0, xap/xdp) now use the same verified
// MFMA transposed-GEMM pattern (per-graph blocks, LDS-staged bf16 activations
// + self-transposed weights) instead of per-thread serial global-load dots,
// which were ~111 us of latency-bound scalar work.

typedef __attribute__((ext_vector_type(8))) __bf16 bf16x8;
typedef __attribute__((ext_vector_type(4))) __bf16 bf16x4;
typedef __attribute__((ext_vector_type(4))) float  floatx4;

#define MFMA16(a, b, c) __builtin_amdgcn_mfma_f32_16x16x32_bf16((a), (b), (c), 0, 0, 0)

__device__ __forceinline__ float leaky(float x) { return x > 0.f ? x : 0.01f * x; }

// ---- workspace layout (bytes) ----
#define WS_WT     0          // bf16 [10][128][128] transposed weights (s*5 + {W1,W2,W3,Wn1,Wn2}), [f][k]
#define WS_XAP    327680     // f32  [8][64][128]  x @ Wne[0:128] + b_node_enc
#define WS_XDP    589824     // f32  [8][64][128]  x @ Wne[128:256]
#define WS_EE0    851968     // bf16 [8][256][128] leaky(edge_attr @ Wee + b)
#define WS_CE     1376256    // f32  [8][2][128]   gg @ W4  + b_edge_upd
#define WS_CN     1384448    // f32  [8][2][128]   gg @ Wn3 + b_node_upd
#define WS_CSROFF 1392640    // int  [8][72]
#define WS_CSREID 1394944    // int  [8][256]
// end ~1.4 MB

#define LDE 136   // padded LDS row stride (elements)

// ============================ prep kernel ============================
__global__ __launch_bounds__(256) void mpn_prep(
    const float* __restrict__ x,     // [8][64][128]
    const float* __restrict__ ea,    // [8][256][128]
    const float* __restrict__ u,     // [8][128]
    const int*   __restrict__ eidx,  // [8][2][256]
    const float* __restrict__ Wne,   // [257][128]
    const float* __restrict__ bne,   // [128]
    const float* __restrict__ Wee,   // [128][128]
    const float* __restrict__ bee,   // [128]
    const float* __restrict__ Wge,   // [128][128]
    const float* __restrict__ bge,   // [128]
    const float* __restrict__ Weu,   // [2][512][128]
    const float* __restrict__ beu,   // [2][128]
    const float* __restrict__ Wnu,   // [2][384][128]
    const float* __restrict__ bnu,   // [2][128]
    char* __restrict__ ws)
{
  // shared pool for the MFMA encoder branches (carved per-branch):
  __shared__ __align__(16) __bf16 smem[384 * LDE];   // 104448 B

  const int b = blockIdx.x, tid = threadIdx.x;
  __bf16* wt  = (__bf16*)(ws + WS_WT);
  float*  xap = (float*)(ws + WS_XAP);
  float*  xdp = (float*)(ws + WS_XDP);
  __bf16* ee0 = (__bf16*)(ws + WS_EE0);
  float*  cev = (float*)(ws + WS_CE);
  float*  cnv = (float*)(ws + WS_CN);
  int* csroff = (int*)(ws + WS_CSROFF);
  int* csreid = (int*)(ws + WS_CSREID);

  if (b < 20) {
    // transpose the 10 [128][128] weight blocks: wt[m][f][k] = src[k][f] (bf16)
    const int m = b >> 1, half = b & 1;
    const int s = m / 5, t = m % 5;
    const float* src = (t < 3) ? (Weu + (size_t)(s*512 + t*128)*128)
                               : (Wnu + (size_t)(s*384 + (t-3)*128)*128);
    const int f = half*64 + (tid & 63);
    const int kq = tid >> 6;
    for (int j = 0; j < 32; ++j) {
      int k = kq*32 + j;
      wt[m*16384 + f*128 + k] = (__bf16)src[k*128 + f];
    }
  } else if (b < 28) {
    // per-graph: gg, ce/cn constant vectors, CSR (deterministic)
    const int g = b - 20;
    __shared__ float gg_sh[128];
    __shared__ int dst_sh[256];
    __shared__ int cnt_sh[64];
    __shared__ int off_sh[65];
    if (tid < 128) {
      float acc = bge[tid];
      for (int k = 0; k < 128; ++k)
        acc += u[g*128 + k] * Wge[k*128 + tid];
      gg_sh[tid] = leaky(acc);
    }
    dst_sh[tid] = eidx[g*512 + 256 + tid];
    __syncthreads();
    {
      const int s = tid >> 7, f = tid & 127;
      float ac = beu[s*128 + f];
      float an = bnu[s*128 + f];
      #pragma unroll 8
      for (int k = 0; k < 128; ++k) {
        float gk = gg_sh[k];
        ac += gk * Weu[(s*512 + 384 + k)*128 + f];
        an += gk * Wnu[(s*384 + 256 + k)*128 + f];
      }
      cev[(g*2 + s)*128 + f] = ac;
      cnv[(g*2 + s)*128 + f] = an;
    }
    if (tid < 64) {
      int c = 0;
      for (int e = 0; e < 256; ++e) c += (dst_sh[e] == tid) ? 1 : 0;
      cnt_sh[tid] = c;
    }
    __syncthreads();
    if (tid == 0) {
      int o = 0;
      for (int n = 0; n < 64; ++n) { off_sh[n] = o; o += cnt_sh[n]; }
      off_sh[64] = o;
    }
    __syncthreads();
    if (tid < 65) csroff[g*72 + tid] = off_sh[tid];
    if (tid < 64) {
      int o = off_sh[tid];
      for (int e = 0; e < 256; ++e)
        if (dst_sh[e] == tid) csreid[g*256 + (o++)] = e;
    }
  } else if (b < 36) {
    // ---- ee0 = leaky(edge_attr @ Wee + bee) via MFMA, one block per graph
    const int g = b - 28;
    __bf16* s_a = smem;              // [256][LDE] bf16 edge_attr
    __bf16* s_w = smem + 256*LDE;    // [128][LDE] bf16 Wee^T ([f][k])
    // stage ea fp32 -> bf16 (256 rows x 32 float4 chunks)
    #pragma unroll
    for (int it = 0; it < 32; ++it) {
      int c = it*256 + tid;
      int row = c >> 5, f4 = (c & 31)*4;
      floatx4 v = *(const floatx4*)&ea[(size_t)(g*256 + row)*128 + f4];
      bf16x4 o;
      #pragma unroll
      for (int r = 0; r < 4; ++r) o[r] = (__bf16)v[r];
      *(bf16x4*)&s_a[row*LDE + f4] = o;
    }
    // stage Wee^T: s_w[f][k] = Wee[k][f]
    #pragma unroll 8
    for (int it = 0; it < 64; ++it) {
      int k = it*2 + (tid >> 7), f = tid & 127;
      s_w[f*LDE + k] = (__bf16)Wee[k*128 + f];
    }
    __syncthreads();
    // wave w -> edges w*64 .. w*64+63 (4 groups of 16)
    const int w = tid >> 6, l = tid & 63, q = l >> 4, xn = l & 15;
    bf16x8 bea[4][4];
    #pragma unroll
    for (int t = 0; t < 4; ++t) {
      int e = w*64 + t*16 + xn;
      #pragma unroll
      for (int c = 0; c < 4; ++c)
        bea[t][c] = *(const bf16x8*)&s_a[e*LDE + c*32 + q*8];
    }
    #pragma unroll
    for (int m = 0; m < 8; ++m) {
      floatx4 acc[4];
      #pragma unroll
      for (int t = 0; t < 4; ++t) acc[t] = (floatx4)0.f;
      const int fr = m*16 + xn;
      #pragma unroll
      for (int c = 0; c < 4; ++c) {
        bf16x8 aw = *(const bf16x8*)&s_w[fr*LDE + c*32 + q*8];
        #pragma unroll
        for (int t = 0; t < 4; ++t) acc[t] = MFMA16(aw, bea[t][c], acc[t]);
      }
      const int f0 = m*16 + q*4;
      floatx4 b4 = *(const floatx4*)&bee[f0];
      #pragma unroll
      for (int t = 0; t < 4; ++t) {
        int e = w*64 + t*16 + xn;
        bf16x4 o;
        #pragma unroll
        for (int r = 0; r < 4; ++r) o[r] = (__bf16)leaky(acc[t][r] + b4[r]);
        *(bf16x4*)&ee0[(size_t)(g*256 + e)*128 + f0] = o;
      }
    }
  } else {
    // ---- xap = x @ Wne[0:128] + bne ; xdp = x @ Wne[128:256]  via MFMA, per graph
    const int g = b - 36;
    __bf16* s_x  = smem;             // [64][LDE]
    __bf16* s_wa = smem + 64*LDE;    // [128][LDE] Wne[0:128]^T
    __bf16* s_wb = smem + 192*LDE;   // [128][LDE] Wne[128:256]^T
    #pragma unroll
    for (int it = 0; it < 8; ++it) {
      int c = it*256 + tid;
      int row = c >> 5, f4 = (c & 31)*4;
      floatx4 v = *(const floatx4*)&x[(size_t)(g*64 + row)*128 + f4];
      bf16x4 o;
      #pragma unroll
      for (int r = 0; r < 4; ++r) o[r] = (__bf16)v[r];
      *(bf16x4*)&s_x[row*LDE + f4] = o;
    }
    #pragma unroll 8
    for (int it = 0; it < 64; ++it) {
      int k = it*2 + (tid >> 7), f = tid & 127;
      s_wa[f*LDE + k] = (__bf16)Wne[k*128 + f];
      s_wb[f*LDE + k] = (__bf16)Wne[(128 + k)*128 + f];
    }
    __syncthreads();
    // wave w -> nodes w*16 .. w*16+15
    const int w = tid >> 6, l = tid & 63, q = l >> 4, xn = l & 15;
    const int i = w*16 + xn;
    bf16x8 bx[4];
    #pragma unroll
    for (int c = 0; c < 4; ++c)
      bx[c] = *(const bf16x8*)&s_x[i*LDE + c*32 + q*8];
    #pragma unroll
    for (int m = 0; m < 8; ++m) {
      floatx4 aa = (floatx4)0.f, ab = (floatx4)0.f;
      const int fr = m*16 + xn;
      #pragma unroll
      for (int c = 0; c < 4; ++c) {
        bf16x8 aw = *(const bf16x8*)&s_wa[fr*LDE + c*32 + q*8];
        aa = MFMA16(aw, bx[c], aa);
      }
      #pragma unroll
      for (int c = 0; c < 4; ++c) {
        bf16x8 aw = *(const bf16x8*)&s_wb[fr*LDE + c*32 + q*8];
        ab = MFMA16(aw, bx[c], ab);
      }
      const int f0 = m*16 + q*4;
      floatx4 bn4 = *(const floatx4*)&bne[f0];
      floatx4 oa;
      #pragma unroll
      for (int r = 0; r < 4; ++r) oa[r] = aa[r] + bn4[r];
      *(floatx4*)&xap[(size_t)(g*64 + i)*128 + f0] = oa;
      *(floatx4*)&xdp[(size_t)(g*64 + i)*128 + f0] = ab;
    }
  }
}

// ============================ main kernel ============================
__global__ __launch_bounds__(256, 1) void mpn_main(
    const float* __restrict__ spdist,  // [8][64][64]
    const int*   __restrict__ eidx,    // [8][2][256]
    const float* __restrict__ Wne,     // row 256 = spdist weight
    const float* __restrict__ wscore,  // [128]
    const float* __restrict__ bscore,  // [1]
    const char* __restrict__ ws,
    float* __restrict__ out)           // [8][256][64]  (g*16384 + e*64 + d), fp32
{
  __shared__ __align__(16) __bf16 s_ee[256*LDE];   // edge state
  __shared__ __align__(16) __bf16 s_h [64*LDE];    // node state
  __shared__ __align__(16) __bf16 s_p2[64*LDE];    // h@W2 (reused as agg)
  __shared__ __align__(16) __bf16 s_p3[64*LDE];    // h@W3 + ce
  __shared__ int s_off[65];
  __shared__ int s_eid[256];

  const __bf16* wt  = (const __bf16*)(ws + WS_WT);
  const float*  xap = (const float*)(ws + WS_XAP);
  const float*  xdp = (const float*)(ws + WS_XDP);
  const __bf16* ee0 = (const __bf16*)(ws + WS_EE0);
  const float*  cev = (const float*)(ws + WS_CE);
  const float*  cnv = (const float*)(ws + WS_CN);
  const int* csroff = (const int*)(ws + WS_CSROFF);
  const int* csreid = (const int*)(ws + WS_CSREID);

  const int tid = threadIdx.x;
  const int w = tid >> 6, l = tid & 63;
  const int q = l >> 4, xn = l & 15;
  const int g = blockIdx.x >> 6, d = blockIdx.x & 63;

  if (tid < 65) s_off[tid] = csroff[g*72 + tid];
  s_eid[tid] = csreid[g*256 + tid];

  // node encoder: h[i][f] = leaky(xap[i][f] + xdp[d][f] + sp(d,i)*wsp[f])
  {
    const int f = tid & 127, ib = tid >> 7;
    float xdpv = xdp[(g*64 + d)*128 + f];
    float wspv = Wne[256*128 + f];
    #pragma unroll
    for (int j = 0; j < 32; ++j) {
      int i = ib + 2*j;
      float sp = spdist[(g*64 + d)*64 + i];
      float v = xap[(g*64 + i)*128 + f] + xdpv + sp*wspv;
      s_h[i*LDE + f] = (__bf16)leaky(v);
    }
  }
  // stage ee0 -> LDS
  #pragma unroll
  for (int it = 0; it < 16; ++it) {
    int c = it*256 + tid;
    int row = c >> 4, col = c & 15;
    *(bf16x8*)&s_ee[row*LDE + col*8] = *(const bf16x8*)&ee0[(g*256 + row)*128 + col*8];
  }

  int mySrc[4], myDst[4];
  #pragma unroll
  for (int t = 0; t < 4; ++t) {
    int e = w*64 + t*16 + xn;
    mySrc[t] = eidx[g*512 + e];
    myDst[t] = eidx[g*512 + 256 + e];
  }
  __syncthreads();

  for (int s = 0; s < 2; ++s) {
    const __bf16* W1T = wt + (s*5 + 0)*16384;
    const __bf16* W2T = wt + (s*5 + 1)*16384;
    const __bf16* W3T = wt + (s*5 + 2)*16384;
    const __bf16* N1T = wt + (s*5 + 3)*16384;
    const __bf16* N2T = wt + (s*5 + 4)*16384;

    // ---- phase 1: s_p2 = h@W2 ; s_p3 = h@W3 + ce  (wave w owns nodes 16w..16w+15)
    {
      bf16x8 bh[4];
      const int i = w*16 + xn;
      #pragma unroll
      for (int c = 0; c < 4; ++c)
        bh[c] = *(const bf16x8*)&s_h[i*LDE + c*32 + q*8];
      #pragma unroll
      for (int m = 0; m < 8; ++m) {
        floatx4 a2 = (floatx4)0.f, a3 = (floatx4)0.f;
        const int fr = m*16 + xn;
        #pragma unroll
        for (int c = 0; c < 4; ++c) {
          bf16x8 aw = *(const bf16x8*)&W2T[fr*128 + c*32 + q*8];
          a2 = MFMA16(aw, bh[c], a2);
        }
        #pragma unroll
        for (int c = 0; c < 4; ++c) {
          bf16x8 aw = *(const bf16x8*)&W3T[fr*128 + c*32 + q*8];
          a3 = MFMA16(aw, bh[c], a3);
        }
        const int f0 = m*16 + q*4;
        floatx4 ce4 = *(const floatx4*)&cev[(g*2 + s)*128 + f0];
        bf16x4 o2, o3;
        #pragma unroll
        for (int r = 0; r < 4; ++r) { o2[r] = (__bf16)a2[r]; o3[r] = (__bf16)(a3[r] + ce4[r]); }
        *(bf16x4*)&s_p2[i*LDE + f0] = o2;
        *(bf16x4*)&s_p3[i*LDE + f0] = o3;
      }
    }
    __syncthreads();

    // ---- phase 2: ee += leaky(ee@W1 + p2[src] + p3[dst])  (wave w owns edges 64w..64w+63;
    //      B-fragments pre-loaded so the in-place update is hazard-free)
    {
      bf16x8 be[4][4];
      #pragma unroll
      for (int t = 0; t < 4; ++t) {
        int e = w*64 + t*16 + xn;
        #pragma unroll
        for (int c = 0; c < 4; ++c)
          be[t][c] = *(const bf16x8*)&s_ee[e*LDE + c*32 + q*8];
      }
      #pragma unroll
      for (int m = 0; m < 8; ++m) {
        floatx4 acc[4];
        #pragma unroll
        for (int t = 0; t < 4; ++t) acc[t] = (floatx4)0.f;
        const int fr = m*16 + xn;
        #pragma unroll
        for (int c = 0; c < 4; ++c) {
          bf16x8 aw = *(const bf16x8*)&W1T[fr*128 + c*32 + q*8];
          #pragma unroll
          for (int t = 0; t < 4; ++t) acc[t] = MFMA16(aw, be[t][c], acc[t]);
        }
        const int f0 = m*16 + q*4;
        #pragma unroll
        for (int t = 0; t < 4; ++t) {
          int e = w*64 + t*16 + xn;
          bf16x4 old = *(const bf16x4*)&s_ee[e*LDE + f0];
          bf16x4 v2  = *(const bf16x4*)&s_p2[mySrc[t]*LDE + f0];
          bf16x4 v3  = *(const bf16x4*)&s_p3[myDst[t]*LDE + f0];
          bf16x4 res;
          #pragma unroll
          for (int r = 0; r < 4; ++r) {
            float vv = acc[t][r] + (float)v2[r] + (float)v3[r];
            res[r] = (__bf16)((float)old[r] + leaky(vv));
          }
          *(bf16x4*)&s_ee[e*LDE + f0] = res;
        }
      }
    }
    __syncthreads();

    if (s == 0) {  // last step's node update is unused -> skip
      // ---- phase 3: agg = segment_sum(ee, dst) -> s_p2 (bf16)
      {
        const int node = w*16 + (l >> 2);
        const int fs = (l & 3)*32;
        float av[32];
        #pragma unroll
        for (int j = 0; j < 32; ++j) av[j] = 0.f;
        const int b0 = s_off[node], b1 = s_off[node + 1];
        for (int idx = b0; idx < b1; ++idx) {
          int e = s_eid[idx];
          #pragma unroll
          for (int cc = 0; cc < 4; ++cc) {
            bf16x8 vv = *(const bf16x8*)&s_ee[e*LDE + fs + cc*8];
            #pragma unroll
            for (int j = 0; j < 8; ++j) av[cc*8 + j] += (float)vv[j];
          }
        }
        #pragma unroll
        for (int cc = 0; cc < 4; ++cc) {
          bf16x8 o;
          #pragma unroll
          for (int j = 0; j < 8; ++j) o[j] = (__bf16)av[cc*8 + j];
          *(bf16x8*)&s_p2[node*LDE + fs + cc*8] = o;
        }
      }
      __syncthreads();
      // ---- phase 4: h += leaky(h@Wn1 + agg@Wn2 + cn)  (in-place; B pre-loaded)
      {
        bf16x8 bh[4], bg[4];
        const int i = w*16 + xn;
        #pragma unroll
        for (int c = 0; c < 4; ++c) {
          bh[c] = *(const bf16x8*)&s_h[i*LDE + c*32 + q*8];
          bg[c] = *(const bf16x8*)&s_p2[i*LDE + c*32 + q*8];
        }
        #pragma unroll
        for (int m = 0; m < 8; ++m) {
          floatx4 acc = (floatx4)0.f;
          const int fr = m*16 + xn;
          #pragma unroll
          for (int c = 0; c < 4; ++c) {
            bf16x8 aw = *(const bf16x8*)&N1T[fr*128 + c*32 + q*8];
            acc = MFMA16(aw, bh[c], acc);
          }
          #pragma unroll
          for (int c = 0; c < 4; ++c) {
            bf16x8 aw = *(const bf16x8*)&N2T[fr*128 + c*32 + q*8];
            acc = MFMA16(aw, bg[c], acc);
          }
          const int f0 = m*16 + q*4;
          floatx4 cn4 = *(const floatx4*)&cnv[(g*2 + s)*128 + f0];
          bf16x4 old = *(const bf16x4*)&s_h[i*LDE + f0];
          bf16x4 res;
          #pragma unroll
          for (int r = 0; r < 4; ++r)
            res[r] = (__bf16)((float)old[r] + leaky(acc[r] + cn4[r]));
          *(bf16x4*)&s_h[i*LDE + f0] = res;
        }
      }
      __syncthreads();
    }
  }

  // ---- scores: out[g, e, d] = ee[e] . wscore + b  (fp32 output)
  {
    const int e = w*64 + l;
    float acc = bscore[0];
    #pragma unroll
    for (int c = 0; c < 16; ++c) {
      bf16x8 vv = *(const bf16x8*)&s_ee[e*LDE + c*8];
      #pragma unroll
      for (int j = 0; j < 8; ++j) acc += (float)vv[j] * wscore[c*8 + j];
    }
    out[g*16384 + e*64 + d] = acc;
  }
}

extern "C" void kernel_launch(void* const* d_in, const int* in_sizes, int n_in,
                              void* d_out, int out_size, void* d_ws, size_t ws_size,
                              hipStream_t stream) {
  (void)in_sizes; (void)n_in; (void)out_size; (void)ws_size;
  const float* x   = (const float*)d_in[0];
  const float* ea  = (const float*)d_in[1];
  const float* u   = (const float*)d_in[2];
  const float* sp  = (const float*)d_in[3];
  const int*   ei  = (const int*)d_in[4];
  const float* Wne = (const float*)d_in[5];
  const float* bne = (const float*)d_in[6];
  const float* Wee = (const float*)d_in[7];
  const float* bee = (const float*)d_in[8];
  const float* Wge = (const float*)d_in[9];
  const float* bge = (const float*)d_in[10];
  const float* Weu = (const float*)d_in[11];
  const float* beu = (const float*)d_in[12];
  const float* Wnu = (const float*)d_in[13];
  const float* bnu = (const float*)d_in[14];
  const float* Wsc = (const float*)d_in[15];
  const float* bsc = (const float*)d_in[16];
  char* ws = (char*)d_ws;

  hipLaunchKernelGGL(mpn_prep, dim3(44), dim3(256), 0, stream,
                     x, ea, u, ei, Wne, bne, Wee, bee, Wge, bge, Weu, beu, Wnu, bnu, ws);
  hipLaunchKernelGGL(mpn_main, dim3(512), dim3(256), 0, stream,
                     sp, ei, Wne, Wsc, bsc, (const char*)ws, (float*)d_out);
}

// Round 7
// 194.849 us; speedup vs baseline: 1.0064x; 1.0064x over previous
//
#include <hip/hip_runtime.h>
#include <hip/hip_bf16.h>

// MPNScoreModule: B=8 graphs, N=64 nodes, E=256 edges, L=128, S=2 steps.
// Round 7: prep identical to round 6. Main kernel: 512-thread blocks
// (8 waves/CU, wave pairs split each GEMM's m-loop) + LDE 136->140
// (280 B row stride = 70 dwords = 6 mod 32 -> conflict-free 16-lane
// fragment reads). In-place phases use load-fragments / barrier /
// compute+write so pair members can't race on shared rows.

typedef __attribute__((ext_vector_type(8))) __bf16 bf16x8;
typedef __attribute__((ext_vector_type(4))) __bf16 bf16x4;
typedef __attribute__((ext_vector_type(4))) float  floatx4;

#define MFMA16(a, b, c) __builtin_amdgcn_mfma_f32_16x16x32_bf16((a), (b), (c), 0, 0, 0)

__device__ __forceinline__ float leaky(float x) { return x > 0.f ? x : 0.01f * x; }

// ---- workspace layout (bytes) ----
#define WS_WT     0          // bf16 [10][128][128] transposed weights (s*5 + {W1,W2,W3,Wn1,Wn2}), [f][k]
#define WS_XAP    327680     // f32  [8][64][128]  x @ Wne[0:128] + b_node_enc
#define WS_XDP    589824     // f32  [8][64][128]  x @ Wne[128:256]
#define WS_EE0    851968     // bf16 [8][256][128] leaky(edge_attr @ Wee + b)
#define WS_CE     1376256    // f32  [8][2][128]   gg @ W4  + b_edge_upd
#define WS_CN     1384448    // f32  [8][2][128]   gg @ Wn3 + b_node_upd
#define WS_CSROFF 1392640    // int  [8][72]
#define WS_CSREID 1394944    // int  [8][256]
// end ~1.4 MB

#define LDE 140   // padded LDS row stride: 280 B = 70 dw = 6 mod 32 -> conflict-free

// ============================ prep kernel (round 6, unchanged) ============================
__global__ __launch_bounds__(256) void mpn_prep(
    const float* __restrict__ x,     // [8][64][128]
    const float* __restrict__ ea,    // [8][256][128]
    const float* __restrict__ u,     // [8][128]
    const int*   __restrict__ eidx,  // [8][2][256]
    const float* __restrict__ Wne,   // [257][128]
    const float* __restrict__ bne,   // [128]
    const float* __restrict__ Wee,   // [128][128]
    const float* __restrict__ bee,   // [128]
    const float* __restrict__ Wge,   // [128][128]
    const float* __restrict__ bge,   // [128]
    const float* __restrict__ Weu,   // [2][512][128]
    const float* __restrict__ beu,   // [2][128]
    const float* __restrict__ Wnu,   // [2][384][128]
    const float* __restrict__ bnu,   // [2][128]
    char* __restrict__ ws)
{
  __shared__ __align__(16) __bf16 smem[384 * LDE];

  const int b = blockIdx.x, tid = threadIdx.x;
  __bf16* wt  = (__bf16*)(ws + WS_WT);
  float*  xap = (float*)(ws + WS_XAP);
  float*  xdp = (float*)(ws + WS_XDP);
  __bf16* ee0 = (__bf16*)(ws + WS_EE0);
  float*  cev = (float*)(ws + WS_CE);
  float*  cnv = (float*)(ws + WS_CN);
  int* csroff = (int*)(ws + WS_CSROFF);
  int* csreid = (int*)(ws + WS_CSREID);

  if (b < 20) {
    const int m = b >> 1, half = b & 1;
    const int s = m / 5, t = m % 5;
    const float* src = (t < 3) ? (Weu + (size_t)(s*512 + t*128)*128)
                               : (Wnu + (size_t)(s*384 + (t-3)*128)*128);
    const int f = half*64 + (tid & 63);
    const int kq = tid >> 6;
    for (int j = 0; j < 32; ++j) {
      int k = kq*32 + j;
      wt[m*16384 + f*128 + k] = (__bf16)src[k*128 + f];
    }
  } else if (b < 28) {
    const int g = b - 20;
    __shared__ float gg_sh[128];
    __shared__ int dst_sh[256];
    __shared__ int cnt_sh[64];
    __shared__ int off_sh[65];
    if (tid < 128) {
      float acc = bge[tid];
      for (int k = 0; k < 128; ++k)
        acc += u[g*128 + k] * Wge[k*128 + tid];
      gg_sh[tid] = leaky(acc);
    }
    dst_sh[tid] = eidx[g*512 + 256 + tid];
    __syncthreads();
    {
      const int s = tid >> 7, f = tid & 127;
      float ac = beu[s*128 + f];
      float an = bnu[s*128 + f];
      #pragma unroll 8
      for (int k = 0; k < 128; ++k) {
        float gk = gg_sh[k];
        ac += gk * Weu[(s*512 + 384 + k)*128 + f];
        an += gk * Wnu[(s*384 + 256 + k)*128 + f];
      }
      cev[(g*2 + s)*128 + f] = ac;
      cnv[(g*2 + s)*128 + f] = an;
    }
    if (tid < 64) {
      int c = 0;
      for (int e = 0; e < 256; ++e) c += (dst_sh[e] == tid) ? 1 : 0;
      cnt_sh[tid] = c;
    }
    __syncthreads();
    if (tid == 0) {
      int o = 0;
      for (int n = 0; n < 64; ++n) { off_sh[n] = o; o += cnt_sh[n]; }
      off_sh[64] = o;
    }
    __syncthreads();
    if (tid < 65) csroff[g*72 + tid] = off_sh[tid];
    if (tid < 64) {
      int o = off_sh[tid];
      for (int e = 0; e < 256; ++e)
        if (dst_sh[e] == tid) csreid[g*256 + (o++)] = e;
    }
  } else if (b < 36) {
    // ee0 = leaky(edge_attr @ Wee + bee) via MFMA, one block per graph
    const int g = b - 28;
    __bf16* s_a = smem;
    __bf16* s_w = smem + 256*LDE;
    #pragma unroll
    for (int it = 0; it < 32; ++it) {
      int c = it*256 + tid;
      int row = c >> 5, f4 = (c & 31)*4;
      floatx4 v = *(const floatx4*)&ea[(size_t)(g*256 + row)*128 + f4];
      bf16x4 o;
      #pragma unroll
      for (int r = 0; r < 4; ++r) o[r] = (__bf16)v[r];
      *(bf16x4*)&s_a[row*LDE + f4] = o;
    }
    #pragma unroll 8
    for (int it = 0; it < 64; ++it) {
      int k = it*2 + (tid >> 7), f = tid & 127;
      s_w[f*LDE + k] = (__bf16)Wee[k*128 + f];
    }
    __syncthreads();
    const int w = tid >> 6, l = tid & 63, q = l >> 4, xn = l & 15;
    bf16x8 bea[4][4];
    #pragma unroll
    for (int t = 0; t < 4; ++t) {
      int e = w*64 + t*16 + xn;
      #pragma unroll
      for (int c = 0; c < 4; ++c)
        bea[t][c] = *(const bf16x8*)&s_a[e*LDE + c*32 + q*8];
    }
    #pragma unroll
    for (int m = 0; m < 8; ++m) {
      floatx4 acc[4];
      #pragma unroll
      for (int t = 0; t < 4; ++t) acc[t] = (floatx4)0.f;
      const int fr = m*16 + xn;
      #pragma unroll
      for (int c = 0; c < 4; ++c) {
        bf16x8 aw = *(const bf16x8*)&s_w[fr*LDE + c*32 + q*8];
        #pragma unroll
        for (int t = 0; t < 4; ++t) acc[t] = MFMA16(aw, bea[t][c], acc[t]);
      }
      const int f0 = m*16 + q*4;
      floatx4 b4 = *(const floatx4*)&bee[f0];
      #pragma unroll
      for (int t = 0; t < 4; ++t) {
        int e = w*64 + t*16 + xn;
        bf16x4 o;
        #pragma unroll
        for (int r = 0; r < 4; ++r) o[r] = (__bf16)leaky(acc[t][r] + b4[r]);
        *(bf16x4*)&ee0[(size_t)(g*256 + e)*128 + f0] = o;
      }
    }
  } else {
    // xap = x @ Wne[0:128] + bne ; xdp = x @ Wne[128:256]  via MFMA, per graph
    const int g = b - 36;
    __bf16* s_x  = smem;
    __bf16* s_wa = smem + 64*LDE;
    __bf16* s_wb = smem + 192*LDE;
    #pragma unroll
    for (int it = 0; it < 8; ++it) {
      int c = it*256 + tid;
      int row = c >> 5, f4 = (c & 31)*4;
      floatx4 v = *(const floatx4*)&x[(size_t)(g*64 + row)*128 + f4];
      bf16x4 o;
      #pragma unroll
      for (int r = 0; r < 4; ++r) o[r] = (__bf16)v[r];
      *(bf16x4*)&s_x[row*LDE + f4] = o;
    }
    #pragma unroll 8
    for (int it = 0; it < 64; ++it) {
      int k = it*2 + (tid >> 7), f = tid & 127;
      s_wa[f*LDE + k] = (__bf16)Wne[k*128 + f];
      s_wb[f*LDE + k] = (__bf16)Wne[(128 + k)*128 + f];
    }
    __syncthreads();
    const int w = tid >> 6, l = tid & 63, q = l >> 4, xn = l & 15;
    const int i = w*16 + xn;
    bf16x8 bx[4];
    #pragma unroll
    for (int c = 0; c < 4; ++c)
      bx[c] = *(const bf16x8*)&s_x[i*LDE + c*32 + q*8];
    #pragma unroll
    for (int m = 0; m < 8; ++m) {
      floatx4 aa = (floatx4)0.f, ab = (floatx4)0.f;
      const int fr = m*16 + xn;
      #pragma unroll
      for (int c = 0; c < 4; ++c) {
        bf16x8 aw = *(const bf16x8*)&s_wa[fr*LDE + c*32 + q*8];
        aa = MFMA16(aw, bx[c], aa);
      }
      #pragma unroll
      for (int c = 0; c < 4; ++c) {
        bf16x8 aw = *(const bf16x8*)&s_wb[fr*LDE + c*32 + q*8];
        ab = MFMA16(aw, bx[c], ab);
      }
      const int f0 = m*16 + q*4;
      floatx4 bn4 = *(const floatx4*)&bne[f0];
      floatx4 oa;
      #pragma unroll
      for (int r = 0; r < 4; ++r) oa[r] = aa[r] + bn4[r];
      *(floatx4*)&xap[(size_t)(g*64 + i)*128 + f0] = oa;
      *(floatx4*)&xdp[(size_t)(g*64 + i)*128 + f0] = ab;
    }
  }
}

// ============================ main kernel ============================
// 512 threads = 8 waves. Wave pair (wp = w>>1) splits each GEMM's m-loop:
// mh = w&1 owns m in [mh*4, mh*4+4). In-place phases: all waves snapshot
// their fragments, __syncthreads, then compute+write (disjoint f-ranges).
__global__ __launch_bounds__(512, 2) void mpn_main(
    const float* __restrict__ spdist,  // [8][64][64]
    const int*   __restrict__ eidx,    // [8][2][256]
    const float* __restrict__ Wne,     // row 256 = spdist weight
    const float* __restrict__ wscore,  // [128]
    const float* __restrict__ bscore,  // [1]
    const char* __restrict__ ws,
    float* __restrict__ out)           // [8][256][64]  (g*16384 + e*64 + d), fp32
{
  __shared__ __align__(16) __bf16 s_ee[256*LDE];   // edge state
  __shared__ __align__(16) __bf16 s_h [64*LDE];    // node state
  __shared__ __align__(16) __bf16 s_p2[64*LDE];    // h@W2 (reused as agg)
  __shared__ __align__(16) __bf16 s_p3[64*LDE];    // h@W3 + ce
  __shared__ int s_off[65];
  __shared__ int s_eid[256];
  __shared__ float s_sc[256];

  const __bf16* wt  = (const __bf16*)(ws + WS_WT);
  const float*  xap = (const float*)(ws + WS_XAP);
  const float*  xdp = (const float*)(ws + WS_XDP);
  const __bf16* ee0 = (const __bf16*)(ws + WS_EE0);
  const float*  cev = (const float*)(ws + WS_CE);
  const float*  cnv = (const float*)(ws + WS_CN);
  const int* csroff = (const int*)(ws + WS_CSROFF);
  const int* csreid = (const int*)(ws + WS_CSREID);

  const int tid = threadIdx.x;
  const int w = tid >> 6, l = tid & 63;
  const int q = l >> 4, xn = l & 15;
  const int wp = w >> 1, mh = w & 1;      // wave pair / m-half
  const int g = blockIdx.x >> 6, d = blockIdx.x & 63;

  if (tid < 65) s_off[tid] = csroff[g*72 + tid];
  if (tid < 256) s_eid[tid] = csreid[g*256 + tid];

  // node encoder: h[i][f] = leaky(xap[i][f] + xdp[d][f] + sp(d,i)*wsp[f])
  {
    const int f = tid & 127, ib = tid >> 7;   // ib in [0,4)
    float xdpv = xdp[(g*64 + d)*128 + f];
    float wspv = Wne[256*128 + f];
    #pragma unroll
    for (int j = 0; j < 16; ++j) {
      int i = ib + 4*j;
      float sp = spdist[(g*64 + d)*64 + i];
      float v = xap[(g*64 + i)*128 + f] + xdpv + sp*wspv;
      s_h[i*LDE + f] = (__bf16)leaky(v);
    }
  }
  // stage ee0 -> LDS (4096 chunks of 16B)
  #pragma unroll
  for (int it = 0; it < 8; ++it) {
    int c = it*512 + tid;
    int row = c >> 4, col = c & 15;
    *(bf16x8*)&s_ee[row*LDE + col*8] = *(const bf16x8*)&ee0[(g*256 + row)*128 + col*8];
  }

  int mySrc[4], myDst[4];
  #pragma unroll
  for (int t = 0; t < 4; ++t) {
    int e = wp*64 + t*16 + xn;
    mySrc[t] = eidx[g*512 + e];
    myDst[t] = eidx[g*512 + 256 + e];
  }
  __syncthreads();

  for (int s = 0; s < 2; ++s) {
    const __bf16* W1T = wt + (s*5 + 0)*16384;
    const __bf16* W2T = wt + (s*5 + 1)*16384;
    const __bf16* W3T = wt + (s*5 + 2)*16384;
    const __bf16* N1T = wt + (s*5 + 3)*16384;
    const __bf16* N2T = wt + (s*5 + 4)*16384;

    // ---- phase 1: s_p2 = h@W2 ; s_p3 = h@W3 + ce
    // wave pair wp owns nodes wp*16..+15; mh owns m in [mh*4, mh*4+4).
    // reads s_h, writes s_p2/s_p3 (no alias) -> no internal barrier needed.
    {
      bf16x8 bh[4];
      const int i = wp*16 + xn;
      #pragma unroll
      for (int c = 0; c < 4; ++c)
        bh[c] = *(const bf16x8*)&s_h[i*LDE + c*32 + q*8];
      #pragma unroll
      for (int mm = 0; mm < 4; ++mm) {
        const int m = mh*4 + mm;
        floatx4 a2 = (floatx4)0.f, a3 = (floatx4)0.f;
        const int fr = m*16 + xn;
        #pragma unroll
        for (int c = 0; c < 4; ++c) {
          bf16x8 aw = *(const bf16x8*)&W2T[fr*128 + c*32 + q*8];
          a2 = MFMA16(aw, bh[c], a2);
        }
        #pragma unroll
        for (int c = 0; c < 4; ++c) {
          bf16x8 aw = *(const bf16x8*)&W3T[fr*128 + c*32 + q*8];
          a3 = MFMA16(aw, bh[c], a3);
        }
        const int f0 = m*16 + q*4;
        floatx4 ce4 = *(const floatx4*)&cev[(g*2 + s)*128 + f0];
        bf16x4 o2, o3;
        #pragma unroll
        for (int r = 0; r < 4; ++r) { o2[r] = (__bf16)a2[r]; o3[r] = (__bf16)(a3[r] + ce4[r]); }
        *(bf16x4*)&s_p2[i*LDE + f0] = o2;
        *(bf16x4*)&s_p3[i*LDE + f0] = o3;
      }
    }
    __syncthreads();

    // ---- phase 2: ee += leaky(ee@W1 + p2[src] + p3[dst])
    // wave pair wp owns edges wp*64..+63; mh splits m. Snapshot -> barrier -> write.
    {
      bf16x8 be[4][4];
      #pragma unroll
      for (int t = 0; t < 4; ++t) {
        int e = wp*64 + t*16 + xn;
        #pragma unroll
        for (int c = 0; c < 4; ++c)
          be[t][c] = *(const bf16x8*)&s_ee[e*LDE + c*32 + q*8];
      }
      __syncthreads();   // all fragments snapshotted before any pair-member writes
      #pragma unroll
      for (int mm = 0; mm < 4; ++mm) {
        const int m = mh*4 + mm;
        floatx4 acc[4];
        #pragma unroll
        for (int t = 0; t < 4; ++t) acc[t] = (floatx4)0.f;
        const int fr = m*16 + xn;
        #pragma unroll
        for (int c = 0; c < 4; ++c) {
          bf16x8 aw = *(const bf16x8*)&W1T[fr*128 + c*32 + q*8];
          #pragma unroll
          for (int t = 0; t < 4; ++t) acc[t] = MFMA16(aw, be[t][c], acc[t]);
        }
        const int f0 = m*16 + q*4;
        #pragma unroll
        for (int t = 0; t < 4; ++t) {
          int e = wp*64 + t*16 + xn;
          bf16x4 old = *(const bf16x4*)&s_ee[e*LDE + f0];
          bf16x4 v2  = *(const bf16x4*)&s_p2[mySrc[t]*LDE + f0];
          bf16x4 v3  = *(const bf16x4*)&s_p3[myDst[t]*LDE + f0];
          bf16x4 res;
          #pragma unroll
          for (int r = 0; r < 4; ++r) {
            float vv = acc[t][r] + (float)v2[r] + (float)v3[r];
            res[r] = (__bf16)((float)old[r] + leaky(vv));
          }
          *(bf16x4*)&s_ee[e*LDE + f0] = res;
        }
      }
    }
    __syncthreads();

    if (s == 0) {  // last step's node update is unused -> skip
      // ---- phase 3: agg = segment_sum(ee, dst) -> s_p2 (bf16)
      // 8 threads per node, 16 features each.
      {
        const int node = tid >> 3;
        const int fs = (tid & 7)*16;
        float av[16];
        #pragma unroll
        for (int j = 0; j < 16; ++j) av[j] = 0.f;
        const int b0 = s_off[node], b1 = s_off[node + 1];
        for (int idx = b0; idx < b1; ++idx) {
          int e = s_eid[idx];
          #pragma unroll
          for (int cc = 0; cc < 2; ++cc) {
            bf16x8 vv = *(const bf16x8*)&s_ee[e*LDE + fs + cc*8];
            #pragma unroll
            for (int j = 0; j < 8; ++j) av[cc*8 + j] += (float)vv[j];
          }
        }
        #pragma unroll
        for (int cc = 0; cc < 2; ++cc) {
          bf16x8 o;
          #pragma unroll
          for (int j = 0; j < 8; ++j) o[j] = (__bf16)av[cc*8 + j];
          *(bf16x8*)&s_p2[node*LDE + fs + cc*8] = o;
        }
      }
      __syncthreads();
      // ---- phase 4: h += leaky(h@Wn1 + agg@Wn2 + cn). Snapshot -> barrier -> write.
      {
        bf16x8 bh[4], bg[4];
        const int i = wp*16 + xn;
        #pragma unroll
        for (int c = 0; c < 4; ++c) {
          bh[c] = *(const bf16x8*)&s_h[i*LDE + c*32 + q*8];
          bg[c] = *(const bf16x8*)&s_p2[i*LDE + c*32 + q*8];
        }
        __syncthreads();
        #pragma unroll
        for (int mm = 0; mm < 4; ++mm) {
          const int m = mh*4 + mm;
          floatx4 acc = (floatx4)0.f;
          const int fr = m*16 + xn;
          #pragma unroll
          for (int c = 0; c < 4; ++c) {
            bf16x8 aw = *(const bf16x8*)&N1T[fr*128 + c*32 + q*8];
            acc = MFMA16(aw, bh[c], acc);
          }
          #pragma unroll
          for (int c = 0; c < 4; ++c) {
            bf16x8 aw = *(const bf16x8*)&N2T[fr*128 + c*32 + q*8];
            acc = MFMA16(aw, bg[c], acc);
          }
          const int f0 = m*16 + q*4;
          floatx4 cn4 = *(const floatx4*)&cnv[(g*2 + s)*128 + f0];
          bf16x4 old = *(const bf16x4*)&s_h[i*LDE + f0];
          bf16x4 res;
          #pragma unroll
          for (int r = 0; r < 4; ++r)
            res[r] = (__bf16)((float)old[r] + leaky(acc[r] + cn4[r]));
          *(bf16x4*)&s_h[i*LDE + f0] = res;
        }
      }
      __syncthreads();
    }
  }

  // ---- scores: out[g, e, d] = ee[e] . wscore + b  (fp32 output)
  // thread halves split the k-range; combine via LDS.
  {
    const int e = tid & 255, hh = tid >> 8;
    float acc = 0.f;
    #pragma unroll
    for (int c = 0; c < 8; ++c) {
      bf16x8 vv = *(const bf16x8*)&s_ee[e*LDE + hh*64 + c*8];
      #pragma unroll
      for (int j = 0; j < 8; ++j) acc += (float)vv[j] * wscore[hh*64 + c*8 + j];
    }
    if (hh == 1) s_sc[e] = acc;
    __syncthreads();
    if (hh == 0) out[g*16384 + e*64 + d] = acc + s_sc[e] + bscore[0];
  }
}

extern "C" void kernel_launch(void* const* d_in, const int* in_sizes, int n_in,
                              void* d_out, int out_size, void* d_ws, size_t ws_size,
                              hipStream_t stream) {
  (void)in_sizes; (void)n_in; (void)out_size; (void)ws_size;
  const float* x   = (const float*)d_in[0];
  const float* ea  = (const float*)d_in[1];
  const float* u   = (const float*)d_in[2];
  const float* sp  = (const float*)d_in[3];
  const int*   ei  = (const int*)d_in[4];
  const float* Wne = (const float*)d_in[5];
  const float* bne = (const float*)d_in[6];
  const float* Wee = (const float*)d_in[7];
  const float* bee = (const float*)d_in[8];
  const float* Wge = (const float*)d_in[9];
  const float* bge = (const float*)d_in[10];
  const float* Weu = (const float*)d_in[11];
  const float* beu = (const float*)d_in[12];
  const float* Wnu = (const float*)d_in[13];
  const float* bnu = (const float*)d_in[14];
  const float* Wsc = (const float*)d_in[15];
  const float* bsc = (const float*)d_in[16];
  char* ws = (char*)d_ws;

  hipLaunchKernelGGL(mpn_prep, dim3(44), dim3(256), 0, stream,
                     x, ea, u, ei, Wne, bne, Wee, bee, Wge, bge, Weu, beu, Wnu, bnu, ws);
  hipLaunchKernelGGL(mpn_main, dim3(512), dim3(512), 0, stream,
                     sp, ei, Wne, Wsc, bsc, (const char*)ws, (float*)d_out);
}

// Round 8
// 160.042 us; speedup vs baseline: 1.2253x; 1.2175x over previous
//
#include <hip/hip_runtime.h>
#include <hip/hip_bf16.h>

// MPNScoreModule: B=8 graphs, N=64 nodes, E=256 edges, L=128, S=2 steps.
// Round 8: round-7 structure, but transposed weights are PRE-PACKED in
// wave-load order: wt[m][(mq*4+c)*64 + lane][8 bf16] so each MFMA A-fragment
// load is base + lane*16B -> fully coalesced 1-KB wave load (16 lines),
// replacing the 64-line scatter (fr*128 stride) that serialized the vmem
// pipe ~16K cyc/phase/CU and pinned MfmaUtil at 7% in rounds 5-7.

typedef __attribute__((ext_vector_type(8))) __bf16 bf16x8;
typedef __attribute__((ext_vector_type(4))) __bf16 bf16x4;
typedef __attribute__((ext_vector_type(4))) float  floatx4;

#define MFMA16(a, b, c) __builtin_amdgcn_mfma_f32_16x16x32_bf16((a), (b), (c), 0, 0, 0)

__device__ __forceinline__ float leaky(float x) { return x > 0.f ? x : 0.01f * x; }

// ---- workspace layout (bytes) ----
#define WS_WT     0          // bf16 [10][16384] PACKED weights: [m][(mq*4+c)*64+l][8]
#define WS_XAP    327680     // f32  [8][64][128]  x @ Wne[0:128] + b_node_enc
#define WS_XDP    589824     // f32  [8][64][128]  x @ Wne[128:256]
#define WS_EE0    851968     // bf16 [8][256][128] leaky(edge_attr @ Wee + b)
#define WS_CE     1376256    // f32  [8][2][128]   gg @ W4  + b_edge_upd
#define WS_CN     1384448    // f32  [8][2][128]   gg @ Wn3 + b_node_upd
#define WS_CSROFF 1392640    // int  [8][72]
#define WS_CSREID 1394944    // int  [8][256]
// end ~1.4 MB

#define LDE 140   // padded LDS row stride: 280 B = 70 dw = 6 mod 32 -> conflict-free

// ============================ prep kernel ============================
__global__ __launch_bounds__(256) void mpn_prep(
    const float* __restrict__ x,     // [8][64][128]
    const float* __restrict__ ea,    // [8][256][128]
    const float* __restrict__ u,     // [8][128]
    const int*   __restrict__ eidx,  // [8][2][256]
    const float* __restrict__ Wne,   // [257][128]
    const float* __restrict__ bne,   // [128]
    const float* __restrict__ Wee,   // [128][128]
    const float* __restrict__ bee,   // [128]
    const float* __restrict__ Wge,   // [128][128]
    const float* __restrict__ bge,   // [128]
    const float* __restrict__ Weu,   // [2][512][128]
    const float* __restrict__ beu,   // [2][128]
    const float* __restrict__ Wnu,   // [2][384][128]
    const float* __restrict__ bnu,   // [2][128]
    char* __restrict__ ws)
{
  __shared__ __align__(16) __bf16 smem[384 * LDE];

  const int b = blockIdx.x, tid = threadIdx.x;
  __bf16* wt  = (__bf16*)(ws + WS_WT);
  float*  xap = (float*)(ws + WS_XAP);
  float*  xdp = (float*)(ws + WS_XDP);
  __bf16* ee0 = (__bf16*)(ws + WS_EE0);
  float*  cev = (float*)(ws + WS_CE);
  float*  cnv = (float*)(ws + WS_CN);
  int* csroff = (int*)(ws + WS_CSROFF);
  int* csreid = (int*)(ws + WS_CSREID);

  if (b < 20) {
    // pack the 10 [128][128] weight blocks into wave-load order:
    // wt[m*16384 + ((mq*4+c)*64 + l)*8 + j] = src[(c*32 + (l>>4)*8 + j)*128 + mq*16 + (l&15)]
    const int m = b >> 1, half = b & 1;
    const int s = m / 5, t = m % 5;
    const float* src = (t < 3) ? (Weu + (size_t)(s*512 + t*128)*128)
                               : (Wnu + (size_t)(s*384 + (t-3)*128)*128);
    for (int it = 0; it < 4; ++it) {
      int p = it*256 + tid;            // 0..1023 (half-matrix worth of fragments)
      int mq = half*4 + (p >> 8);      // 0..7
      int c  = (p >> 6) & 3;
      int l  = p & 63;
      int fr = mq*16 + (l & 15);
      int kb = c*32 + (l >> 4)*8;
      __bf16* dst = &wt[m*16384 + ((mq*4 + c)*64 + l)*8];
      #pragma unroll
      for (int j = 0; j < 8; ++j)
        dst[j] = (__bf16)src[(kb + j)*128 + fr];
    }
  } else if (b < 28) {
    const int g = b - 20;
    __shared__ float gg_sh[128];
    __shared__ int dst_sh[256];
    __shared__ int cnt_sh[64];
    __shared__ int off_sh[65];
    if (tid < 128) {
      float acc = bge[tid];
      for (int k = 0; k < 128; ++k)
        acc += u[g*128 + k] * Wge[k*128 + tid];
      gg_sh[tid] = leaky(acc);
    }
    dst_sh[tid] = eidx[g*512 + 256 + tid];
    __syncthreads();
    {
      const int s = tid >> 7, f = tid & 127;
      float ac = beu[s*128 + f];
      float an = bnu[s*128 + f];
      #pragma unroll 8
      for (int k = 0; k < 128; ++k) {
        float gk = gg_sh[k];
        ac += gk * Weu[(s*512 + 384 + k)*128 + f];
        an += gk * Wnu[(s*384 + 256 + k)*128 + f];
      }
      cev[(g*2 + s)*128 + f] = ac;
      cnv[(g*2 + s)*128 + f] = an;
    }
    if (tid < 64) {
      int c = 0;
      for (int e = 0; e < 256; ++e) c += (dst_sh[e] == tid) ? 1 : 0;
      cnt_sh[tid] = c;
    }
    __syncthreads();
    if (tid == 0) {
      int o = 0;
      for (int n = 0; n < 64; ++n) { off_sh[n] = o; o += cnt_sh[n]; }
      off_sh[64] = o;
    }
    __syncthreads();
    if (tid < 65) csroff[g*72 + tid] = off_sh[tid];
    if (tid < 64) {
      int o = off_sh[tid];
      for (int e = 0; e < 256; ++e)
        if (dst_sh[e] == tid) csreid[g*256 + (o++)] = e;
    }
  } else if (b < 36) {
    // ee0 = leaky(edge_attr @ Wee + bee) via MFMA, one block per graph
    const int g = b - 28;
    __bf16* s_a = smem;
    __bf16* s_w = smem + 256*LDE;
    #pragma unroll
    for (int it = 0; it < 32; ++it) {
      int c = it*256 + tid;
      int row = c >> 5, f4 = (c & 31)*4;
      floatx4 v = *(const floatx4*)&ea[(size_t)(g*256 + row)*128 + f4];
      bf16x4 o;
      #pragma unroll
      for (int r = 0; r < 4; ++r) o[r] = (__bf16)v[r];
      *(bf16x4*)&s_a[row*LDE + f4] = o;
    }
    #pragma unroll 8
    for (int it = 0; it < 64; ++it) {
      int k = it*2 + (tid >> 7), f = tid & 127;
      s_w[f*LDE + k] = (__bf16)Wee[k*128 + f];
    }
    __syncthreads();
    const int w = tid >> 6, l = tid & 63, q = l >> 4, xn = l & 15;
    bf16x8 bea[4][4];
    #pragma unroll
    for (int t = 0; t < 4; ++t) {
      int e = w*64 + t*16 + xn;
      #pragma unroll
      for (int c = 0; c < 4; ++c)
        bea[t][c] = *(const bf16x8*)&s_a[e*LDE + c*32 + q*8];
    }
    #pragma unroll
    for (int m = 0; m < 8; ++m) {
      floatx4 acc[4];
      #pragma unroll
      for (int t = 0; t < 4; ++t) acc[t] = (floatx4)0.f;
      const int fr = m*16 + xn;
      #pragma unroll
      for (int c = 0; c < 4; ++c) {
        bf16x8 aw = *(const bf16x8*)&s_w[fr*LDE + c*32 + q*8];
        #pragma unroll
        for (int t = 0; t < 4; ++t) acc[t] = MFMA16(aw, bea[t][c], acc[t]);
      }
      const int f0 = m*16 + q*4;
      floatx4 b4 = *(const floatx4*)&bee[f0];
      #pragma unroll
      for (int t = 0; t < 4; ++t) {
        int e = w*64 + t*16 + xn;
        bf16x4 o;
        #pragma unroll
        for (int r = 0; r < 4; ++r) o[r] = (__bf16)leaky(acc[t][r] + b4[r]);
        *(bf16x4*)&ee0[(size_t)(g*256 + e)*128 + f0] = o;
      }
    }
  } else {
    // xap = x @ Wne[0:128] + bne ; xdp = x @ Wne[128:256]  via MFMA, per graph
    const int g = b - 36;
    __bf16* s_x  = smem;
    __bf16* s_wa = smem + 64*LDE;
    __bf16* s_wb = smem + 192*LDE;
    #pragma unroll
    for (int it = 0; it < 8; ++it) {
      int c = it*256 + tid;
      int row = c >> 5, f4 = (c & 31)*4;
      floatx4 v = *(const floatx4*)&x[(size_t)(g*64 + row)*128 + f4];
      bf16x4 o;
      #pragma unroll
      for (int r = 0; r < 4; ++r) o[r] = (__bf16)v[r];
      *(bf16x4*)&s_x[row*LDE + f4] = o;
    }
    #pragma unroll 8
    for (int it = 0; it < 64; ++it) {
      int k = it*2 + (tid >> 7), f = tid & 127;
      s_wa[f*LDE + k] = (__bf16)Wne[k*128 + f];
      s_wb[f*LDE + k] = (__bf16)Wne[(128 + k)*128 + f];
    }
    __syncthreads();
    const int w = tid >> 6, l = tid & 63, q = l >> 4, xn = l & 15;
    const int i = w*16 + xn;
    bf16x8 bx[4];
    #pragma unroll
    for (int c = 0; c < 4; ++c)
      bx[c] = *(const bf16x8*)&s_x[i*LDE + c*32 + q*8];
    #pragma unroll
    for (int m = 0; m < 8; ++m) {
      floatx4 aa = (floatx4)0.f, ab = (floatx4)0.f;
      const int fr = m*16 + xn;
      #pragma unroll
      for (int c = 0; c < 4; ++c) {
        bf16x8 aw = *(const bf16x8*)&s_wa[fr*LDE + c*32 + q*8];
        aa = MFMA16(aw, bx[c], aa);
      }
      #pragma unroll
      for (int c = 0; c < 4; ++c) {
        bf16x8 aw = *(const bf16x8*)&s_wb[fr*LDE + c*32 + q*8];
        ab = MFMA16(aw, bx[c], ab);
      }
      const int f0 = m*16 + q*4;
      floatx4 bn4 = *(const floatx4*)&bne[f0];
      floatx4 oa;
      #pragma unroll
      for (int r = 0; r < 4; ++r) oa[r] = aa[r] + bn4[r];
      *(floatx4*)&xap[(size_t)(g*64 + i)*128 + f0] = oa;
      *(floatx4*)&xdp[(size_t)(g*64 + i)*128 + f0] = ab;
    }
  }
}

// ============================ main kernel ============================
// 512 threads = 8 waves. Wave pair (wp = w>>1) splits each GEMM's m-loop:
// mh = w&1 owns m in [mh*4, mh*4+4). Packed weight fragment for (m,c):
// base + ((m*4+c)*64 + lane)*8  -> coalesced 1-KB wave load.
__global__ __launch_bounds__(512, 2) void mpn_main(
    const float* __restrict__ spdist,  // [8][64][64]
    const int*   __restrict__ eidx,    // [8][2][256]
    const float* __restrict__ Wne,     // row 256 = spdist weight
    const float* __restrict__ wscore,  // [128]
    const float* __restrict__ bscore,  // [1]
    const char* __restrict__ ws,
    float* __restrict__ out)           // [8][256][64]  (g*16384 + e*64 + d), fp32
{
  __shared__ __align__(16) __bf16 s_ee[256*LDE];   // edge state
  __shared__ __align__(16) __bf16 s_h [64*LDE];    // node state
  __shared__ __align__(16) __bf16 s_p2[64*LDE];    // h@W2 (reused as agg)
  __shared__ __align__(16) __bf16 s_p3[64*LDE];    // h@W3 + ce
  __shared__ int s_off[65];
  __shared__ int s_eid[256];
  __shared__ float s_sc[256];

  const __bf16* wt  = (const __bf16*)(ws + WS_WT);
  const float*  xap = (const float*)(ws + WS_XAP);
  const float*  xdp = (const float*)(ws + WS_XDP);
  const __bf16* ee0 = (const __bf16*)(ws + WS_EE0);
  const float*  cev = (const float*)(ws + WS_CE);
  const float*  cnv = (const float*)(ws + WS_CN);
  const int* csroff = (const int*)(ws + WS_CSROFF);
  const int* csreid = (const int*)(ws + WS_CSREID);

  const int tid = threadIdx.x;
  const int w = tid >> 6, l = tid & 63;
  const int q = l >> 4, xn = l & 15;
  const int wp = w >> 1, mh = w & 1;      // wave pair / m-half
  const int lane8 = l*8;                  // packed-fragment lane offset
  const int g = blockIdx.x >> 6, d = blockIdx.x & 63;

  if (tid < 65) s_off[tid] = csroff[g*72 + tid];
  if (tid < 256) s_eid[tid] = csreid[g*256 + tid];

  // node encoder: h[i][f] = leaky(xap[i][f] + xdp[d][f] + sp(d,i)*wsp[f])
  {
    const int f = tid & 127, ib = tid >> 7;   // ib in [0,4)
    float xdpv = xdp[(g*64 + d)*128 + f];
    float wspv = Wne[256*128 + f];
    #pragma unroll
    for (int j = 0; j < 16; ++j) {
      int i = ib + 4*j;
      float sp = spdist[(g*64 + d)*64 + i];
      float v = xap[(g*64 + i)*128 + f] + xdpv + sp*wspv;
      s_h[i*LDE + f] = (__bf16)leaky(v);
    }
  }
  // stage ee0 -> LDS (4096 chunks of 16B)
  #pragma unroll
  for (int it = 0; it < 8; ++it) {
    int c = it*512 + tid;
    int row = c >> 4, col = c & 15;
    *(bf16x8*)&s_ee[row*LDE + col*8] = *(const bf16x8*)&ee0[(g*256 + row)*128 + col*8];
  }

  int mySrc[4], myDst[4];
  #pragma unroll
  for (int t = 0; t < 4; ++t) {
    int e = wp*64 + t*16 + xn;
    mySrc[t] = eidx[g*512 + e];
    myDst[t] = eidx[g*512 + 256 + e];
  }
  __syncthreads();

  for (int s = 0; s < 2; ++s) {
    const __bf16* W1T = wt + (s*5 + 0)*16384;
    const __bf16* W2T = wt + (s*5 + 1)*16384;
    const __bf16* W3T = wt + (s*5 + 2)*16384;
    const __bf16* N1T = wt + (s*5 + 3)*16384;
    const __bf16* N2T = wt + (s*5 + 4)*16384;

    // ---- phase 1: s_p2 = h@W2 ; s_p3 = h@W3 + ce
    {
      bf16x8 bh[4];
      const int i = wp*16 + xn;
      #pragma unroll
      for (int c = 0; c < 4; ++c)
        bh[c] = *(const bf16x8*)&s_h[i*LDE + c*32 + q*8];
      #pragma unroll
      for (int mm = 0; mm < 4; ++mm) {
        const int m = mh*4 + mm;
        floatx4 a2 = (floatx4)0.f, a3 = (floatx4)0.f;
        #pragma unroll
        for (int c = 0; c < 4; ++c) {
          bf16x8 aw = *(const bf16x8*)&W2T[(m*4 + c)*512 + lane8];
          a2 = MFMA16(aw, bh[c], a2);
        }
        #pragma unroll
        for (int c = 0; c < 4; ++c) {
          bf16x8 aw = *(const bf16x8*)&W3T[(m*4 + c)*512 + lane8];
          a3 = MFMA16(aw, bh[c], a3);
        }
        const int f0 = m*16 + q*4;
        floatx4 ce4 = *(const floatx4*)&cev[(g*2 + s)*128 + f0];
        bf16x4 o2, o3;
        #pragma unroll
        for (int r = 0; r < 4; ++r) { o2[r] = (__bf16)a2[r]; o3[r] = (__bf16)(a3[r] + ce4[r]); }
        *(bf16x4*)&s_p2[i*LDE + f0] = o2;
        *(bf16x4*)&s_p3[i*LDE + f0] = o3;
      }
    }
    __syncthreads();

    // ---- phase 2: ee += leaky(ee@W1 + p2[src] + p3[dst]). Snapshot -> barrier -> write.
    {
      bf16x8 be[4][4];
      #pragma unroll
      for (int t = 0; t < 4; ++t) {
        int e = wp*64 + t*16 + xn;
        #pragma unroll
        for (int c = 0; c < 4; ++c)
          be[t][c] = *(const bf16x8*)&s_ee[e*LDE + c*32 + q*8];
      }
      __syncthreads();
      #pragma unroll
      for (int mm = 0; mm < 4; ++mm) {
        const int m = mh*4 + mm;
        floatx4 acc[4];
        #pragma unroll
        for (int t = 0; t < 4; ++t) acc[t] = (floatx4)0.f;
        #pragma unroll
        for (int c = 0; c < 4; ++c) {
          bf16x8 aw = *(const bf16x8*)&W1T[(m*4 + c)*512 + lane8];
          #pragma unroll
          for (int t = 0; t < 4; ++t) acc[t] = MFMA16(aw, be[t][c], acc[t]);
        }
        const int f0 = m*16 + q*4;
        #pragma unroll
        for (int t = 0; t < 4; ++t) {
          int e = wp*64 + t*16 + xn;
          bf16x4 old = *(const bf16x4*)&s_ee[e*LDE + f0];
          bf16x4 v2  = *(const bf16x4*)&s_p2[mySrc[t]*LDE + f0];
          bf16x4 v3  = *(const bf16x4*)&s_p3[myDst[t]*LDE + f0];
          bf16x4 res;
          #pragma unroll
          for (int r = 0; r < 4; ++r) {
            float vv = acc[t][r] + (float)v2[r] + (float)v3[r];
            res[r] = (__bf16)((float)old[r] + leaky(vv));
          }
          *(bf16x4*)&s_ee[e*LDE + f0] = res;
        }
      }
    }
    __syncthreads();

    if (s == 0) {  // last step's node update is unused -> skip
      // ---- phase 3: agg = segment_sum(ee, dst) -> s_p2 (bf16). 8 thr/node.
      {
        const int node = tid >> 3;
        const int fs = (tid & 7)*16;
        float av[16];
        #pragma unroll
        for (int j = 0; j < 16; ++j) av[j] = 0.f;
        const int b0 = s_off[node], b1 = s_off[node + 1];
        for (int idx = b0; idx < b1; ++idx) {
          int e = s_eid[idx];
          #pragma unroll
          for (int cc = 0; cc < 2; ++cc) {
            bf16x8 vv = *(const bf16x8*)&s_ee[e*LDE + fs + cc*8];
            #pragma unroll
            for (int j = 0; j < 8; ++j) av[cc*8 + j] += (float)vv[j];
          }
        }
        #pragma unroll
        for (int cc = 0; cc < 2; ++cc) {
          bf16x8 o;
          #pragma unroll
          for (int j = 0; j < 8; ++j) o[j] = (__bf16)av[cc*8 + j];
          *(bf16x8*)&s_p2[node*LDE + fs + cc*8] = o;
        }
      }
      __syncthreads();
      // ---- phase 4: h += leaky(h@Wn1 + agg@Wn2 + cn). Snapshot -> barrier -> write.
      {
        bf16x8 bh[4], bg[4];
        const int i = wp*16 + xn;
        #pragma unroll
        for (int c = 0; c < 4; ++c) {
          bh[c] = *(const bf16x8*)&s_h[i*LDE + c*32 + q*8];
          bg[c] = *(const bf16x8*)&s_p2[i*LDE + c*32 + q*8];
        }
        __syncthreads();
        #pragma unroll
        for (int mm = 0; mm < 4; ++mm) {
          const int m = mh*4 + mm;
          floatx4 acc = (floatx4)0.f;
          #pragma unroll
          for (int c = 0; c < 4; ++c) {
            bf16x8 aw = *(const bf16x8*)&N1T[(m*4 + c)*512 + lane8];
            acc = MFMA16(aw, bh[c], acc);
          }
          #pragma unroll
          for (int c = 0; c < 4; ++c) {
            bf16x8 aw = *(const bf16x8*)&N2T[(m*4 + c)*512 + lane8];
            acc = MFMA16(aw, bg[c], acc);
          }
          const int f0 = m*16 + q*4;
          floatx4 cn4 = *(const floatx4*)&cnv[(g*2 + s)*128 + f0];
          bf16x4 old = *(const bf16x4*)&s_h[i*LDE + f0];
          bf16x4 res;
          #pragma unroll
          for (int r = 0; r < 4; ++r)
            res[r] = (__bf16)((float)old[r] + leaky(acc[r] + cn4[r]));
          *(bf16x4*)&s_h[i*LDE + f0] = res;
        }
      }
      __syncthreads();
    }
  }

  // ---- scores: out[g, e, d] = ee[e] . wscore + b  (fp32 output)
  {
    const int e = tid & 255, hh = tid >> 8;
    float acc = 0.f;
    #pragma unroll
    for (int c = 0; c < 8; ++c) {
      bf16x8 vv = *(const bf16x8*)&s_ee[e*LDE + hh*64 + c*8];
      #pragma unroll
      for (int j = 0; j < 8; ++j) acc += (float)vv[j] * wscore[hh*64 + c*8 + j];
    }
    if (hh == 1) s_sc[e] = acc;
    __syncthreads();
    if (hh == 0) out[g*16384 + e*64 + d] = acc + s_sc[e] + bscore[0];
  }
}

extern "C" void kernel_launch(void* const* d_in, const int* in_sizes, int n_in,
                              void* d_out, int out_size, void* d_ws, size_t ws_size,
                              hipStream_t stream) {
  (void)in_sizes; (void)n_in; (void)out_size; (void)ws_size;
  const float* x   = (const float*)d_in[0];
  const float* ea  = (const float*)d_in[1];
  const float* u   = (const float*)d_in[2];
  const float* sp  = (const float*)d_in[3];
  const int*   ei  = (const int*)d_in[4];
  const float* Wne = (const float*)d_in[5];
  const float* bne = (const float*)d_in[6];
  const float* Wee = (const float*)d_in[7];
  const float* bee = (const float*)d_in[8];
  const float* Wge = (const float*)d_in[9];
  const float* bge = (const float*)d_in[10];
  const float* Weu = (const float*)d_in[11];
  const float* beu = (const float*)d_in[12];
  const float* Wnu = (const float*)d_in[13];
  const float* bnu = (const float*)d_in[14];
  const float* Wsc = (const float*)d_in[15];
  const float* bsc = (const float*)d_in[16];
  char* ws = (char*)d_ws;

  hipLaunchKernelGGL(mpn_prep, dim3(44), dim3(256), 0, stream,
                     x, ea, u, ei, Wne, bne, Wee, bee, Wge, bge, Weu, beu, Wnu, bnu, ws);
  hipLaunchKernelGGL(mpn_main, dim3(512), dim3(512), 0, stream,
                     sp, ei, Wne, Wsc, bsc, (const char*)ws, (float*)d_out);
}

// Round 9
// 158.290 us; speedup vs baseline: 1.2388x; 1.0111x over previous
//
#include <hip/hip_runtime.h>
#include <hip/hip_bf16.h>

// MPNScoreModule: B=8 graphs, N=64 nodes, E=256 edges, L=128, S=2 steps.
// Round 9: round-8 prep unchanged. Main: wave->work mapping flipped so each
// wave owns feature-slice m = wave-id for ALL rows. Each wave keeps its 4
// weight fragments per matrix in registers for the whole phase; the block
// loads each weight matrix from L2 exactly once (256 KB/block vs round-8's
// 1 MB of 4x-redundant fragment loads). In-place phases: compute all accs
// (reads) -> barrier -> epilogue writes (wave-exclusive f-slices).

typedef __attribute__((ext_vector_type(8))) __bf16 bf16x8;
typedef __attribute__((ext_vector_type(4))) __bf16 bf16x4;
typedef __attribute__((ext_vector_type(4))) float  floatx4;

#define MFMA16(a, b, c) __builtin_amdgcn_mfma_f32_16x16x32_bf16((a), (b), (c), 0, 0, 0)

__device__ __forceinline__ float leaky(float x) { return x > 0.f ? x : 0.01f * x; }

// ---- workspace layout (bytes) ----
#define WS_WT     0          // bf16 [10][16384] PACKED weights: [m][(mq*4+c)*64+l][8]
#define WS_XAP    327680     // f32  [8][64][128]  x @ Wne[0:128] + b_node_enc
#define WS_XDP    589824     // f32  [8][64][128]  x @ Wne[128:256]
#define WS_EE0    851968     // bf16 [8][256][128] leaky(edge_attr @ Wee + b)
#define WS_CE     1376256    // f32  [8][2][128]   gg @ W4  + b_edge_upd
#define WS_CN     1384448    // f32  [8][2][128]   gg @ Wn3 + b_node_upd
#define WS_CSROFF 1392640    // int  [8][72]
#define WS_CSREID 1394944    // int  [8][256]
// end ~1.4 MB

#define LDE 140   // padded LDS row stride: 280 B = 70 dw = 6 mod 32 -> conflict-free

// ============================ prep kernel (round 8, unchanged) ============================
__global__ __launch_bounds__(256) void mpn_prep(
    const float* __restrict__ x,     // [8][64][128]
    const float* __restrict__ ea,    // [8][256][128]
    const float* __restrict__ u,     // [8][128]
    const int*   __restrict__ eidx,  // [8][2][256]
    const float* __restrict__ Wne,   // [257][128]
    const float* __restrict__ bne,   // [128]
    const float* __restrict__ Wee,   // [128][128]
    const float* __restrict__ bee,   // [128]
    const float* __restrict__ Wge,   // [128][128]
    const float* __restrict__ bge,   // [128]
    const float* __restrict__ Weu,   // [2][512][128]
    const float* __restrict__ beu,   // [2][128]
    const float* __restrict__ Wnu,   // [2][384][128]
    const float* __restrict__ bnu,   // [2][128]
    char* __restrict__ ws)
{
  __shared__ __align__(16) __bf16 smem[384 * LDE];

  const int b = blockIdx.x, tid = threadIdx.x;
  __bf16* wt  = (__bf16*)(ws + WS_WT);
  float*  xap = (float*)(ws + WS_XAP);
  float*  xdp = (float*)(ws + WS_XDP);
  __bf16* ee0 = (__bf16*)(ws + WS_EE0);
  float*  cev = (float*)(ws + WS_CE);
  float*  cnv = (float*)(ws + WS_CN);
  int* csroff = (int*)(ws + WS_CSROFF);
  int* csreid = (int*)(ws + WS_CSREID);

  if (b < 20) {
    // pack the 10 [128][128] weight blocks into wave-load order:
    // wt[m*16384 + ((mq*4+c)*64 + l)*8 + j] = src[(c*32 + (l>>4)*8 + j)*128 + mq*16 + (l&15)]
    const int m = b >> 1, half = b & 1;
    const int s = m / 5, t = m % 5;
    const float* src = (t < 3) ? (Weu + (size_t)(s*512 + t*128)*128)
                               : (Wnu + (size_t)(s*384 + (t-3)*128)*128);
    for (int it = 0; it < 4; ++it) {
      int p = it*256 + tid;
      int mq = half*4 + (p >> 8);
      int c  = (p >> 6) & 3;
      int l  = p & 63;
      int fr = mq*16 + (l & 15);
      int kb = c*32 + (l >> 4)*8;
      __bf16* dst = &wt[m*16384 + ((mq*4 + c)*64 + l)*8];
      #pragma unroll
      for (int j = 0; j < 8; ++j)
        dst[j] = (__bf16)src[(kb + j)*128 + fr];
    }
  } else if (b < 28) {
    const int g = b - 20;
    __shared__ float gg_sh[128];
    __shared__ int dst_sh[256];
    __shared__ int cnt_sh[64];
    __shared__ int off_sh[65];
    if (tid < 128) {
      float acc = bge[tid];
      for (int k = 0; k < 128; ++k)
        acc += u[g*128 + k] * Wge[k*128 + tid];
      gg_sh[tid] = leaky(acc);
    }
    dst_sh[tid] = eidx[g*512 + 256 + tid];
    __syncthreads();
    {
      const int s = tid >> 7, f = tid & 127;
      float ac = beu[s*128 + f];
      float an = bnu[s*128 + f];
      #pragma unroll 8
      for (int k = 0; k < 128; ++k) {
        float gk = gg_sh[k];
        ac += gk * Weu[(s*512 + 384 + k)*128 + f];
        an += gk * Wnu[(s*384 + 256 + k)*128 + f];
      }
      cev[(g*2 + s)*128 + f] = ac;
      cnv[(g*2 + s)*128 + f] = an;
    }
    if (tid < 64) {
      int c = 0;
      for (int e = 0; e < 256; ++e) c += (dst_sh[e] == tid) ? 1 : 0;
      cnt_sh[tid] = c;
    }
    __syncthreads();
    if (tid == 0) {
      int o = 0;
      for (int n = 0; n < 64; ++n) { off_sh[n] = o; o += cnt_sh[n]; }
      off_sh[64] = o;
    }
    __syncthreads();
    if (tid < 65) csroff[g*72 + tid] = off_sh[tid];
    if (tid < 64) {
      int o = off_sh[tid];
      for (int e = 0; e < 256; ++e)
        if (dst_sh[e] == tid) csreid[g*256 + (o++)] = e;
    }
  } else if (b < 36) {
    // ee0 = leaky(edge_attr @ Wee + bee) via MFMA, one block per graph
    const int g = b - 28;
    __bf16* s_a = smem;
    __bf16* s_w = smem + 256*LDE;
    #pragma unroll
    for (int it = 0; it < 32; ++it) {
      int c = it*256 + tid;
      int row = c >> 5, f4 = (c & 31)*4;
      floatx4 v = *(const floatx4*)&ea[(size_t)(g*256 + row)*128 + f4];
      bf16x4 o;
      #pragma unroll
      for (int r = 0; r < 4; ++r) o[r] = (__bf16)v[r];
      *(bf16x4*)&s_a[row*LDE + f4] = o;
    }
    #pragma unroll 8
    for (int it = 0; it < 64; ++it) {
      int k = it*2 + (tid >> 7), f = tid & 127;
      s_w[f*LDE + k] = (__bf16)Wee[k*128 + f];
    }
    __syncthreads();
    const int w = tid >> 6, l = tid & 63, q = l >> 4, xn = l & 15;
    bf16x8 bea[4][4];
    #pragma unroll
    for (int t = 0; t < 4; ++t) {
      int e = w*64 + t*16 + xn;
      #pragma unroll
      for (int c = 0; c < 4; ++c)
        bea[t][c] = *(const bf16x8*)&s_a[e*LDE + c*32 + q*8];
    }
    #pragma unroll
    for (int m = 0; m < 8; ++m) {
      floatx4 acc[4];
      #pragma unroll
      for (int t = 0; t < 4; ++t) acc[t] = (floatx4)0.f;
      const int fr = m*16 + xn;
      #pragma unroll
      for (int c = 0; c < 4; ++c) {
        bf16x8 aw = *(const bf16x8*)&s_w[fr*LDE + c*32 + q*8];
        #pragma unroll
        for (int t = 0; t < 4; ++t) acc[t] = MFMA16(aw, bea[t][c], acc[t]);
      }
      const int f0 = m*16 + q*4;
      floatx4 b4 = *(const floatx4*)&bee[f0];
      #pragma unroll
      for (int t = 0; t < 4; ++t) {
        int e = w*64 + t*16 + xn;
        bf16x4 o;
        #pragma unroll
        for (int r = 0; r < 4; ++r) o[r] = (__bf16)leaky(acc[t][r] + b4[r]);
        *(bf16x4*)&ee0[(size_t)(g*256 + e)*128 + f0] = o;
      }
    }
  } else {
    // xap = x @ Wne[0:128] + bne ; xdp = x @ Wne[128:256]  via MFMA, per graph
    const int g = b - 36;
    __bf16* s_x  = smem;
    __bf16* s_wa = smem + 64*LDE;
    __bf16* s_wb = smem + 192*LDE;
    #pragma unroll
    for (int it = 0; it < 8; ++it) {
      int c = it*256 + tid;
      int row = c >> 5, f4 = (c & 31)*4;
      floatx4 v = *(const floatx4*)&x[(size_t)(g*64 + row)*128 + f4];
      bf16x4 o;
      #pragma unroll
      for (int r = 0; r < 4; ++r) o[r] = (__bf16)v[r];
      *(bf16x4*)&s_x[row*LDE + f4] = o;
    }
    #pragma unroll 8
    for (int it = 0; it < 64; ++it) {
      int k = it*2 + (tid >> 7), f = tid & 127;
      s_wa[f*LDE + k] = (__bf16)Wne[k*128 + f];
      s_wb[f*LDE + k] = (__bf16)Wne[(128 + k)*128 + f];
    }
    __syncthreads();
    const int w = tid >> 6, l = tid & 63, q = l >> 4, xn = l & 15;
    const int i = w*16 + xn;
    bf16x8 bx[4];
    #pragma unroll
    for (int c = 0; c < 4; ++c)
      bx[c] = *(const bf16x8*)&s_x[i*LDE + c*32 + q*8];
    #pragma unroll
    for (int m = 0; m < 8; ++m) {
      floatx4 aa = (floatx4)0.f, ab = (floatx4)0.f;
      const int fr = m*16 + xn;
      #pragma unroll
      for (int c = 0; c < 4; ++c) {
        bf16x8 aw = *(const bf16x8*)&s_wa[fr*LDE + c*32 + q*8];
        aa = MFMA16(aw, bx[c], aa);
      }
      #pragma unroll
      for (int c = 0; c < 4; ++c) {
        bf16x8 aw = *(const bf16x8*)&s_wb[fr*LDE + c*32 + q*8];
        ab = MFMA16(aw, bx[c], ab);
      }
      const int f0 = m*16 + q*4;
      floatx4 bn4 = *(const floatx4*)&bne[f0];
      floatx4 oa;
      #pragma unroll
      for (int r = 0; r < 4; ++r) oa[r] = aa[r] + bn4[r];
      *(floatx4*)&xap[(size_t)(g*64 + i)*128 + f0] = oa;
      *(floatx4*)&xdp[(size_t)(g*64 + i)*128 + f0] = ab;
    }
  }
}

// ============================ main kernel ============================
// 512 threads = 8 waves. Wave w owns feature-slice m = w (f-range w*16..+16)
// for ALL rows. Weight fragments (w, c=0..3) live in registers per phase;
// block loads each weight matrix from L2 exactly once.
__global__ __launch_bounds__(512, 2) void mpn_main(
    const float* __restrict__ spdist,  // [8][64][64]
    const int*   __restrict__ eidx,    // [8][2][256]
    const float* __restrict__ Wne,     // row 256 = spdist weight
    const float* __restrict__ wscore,  // [128]
    const float* __restrict__ bscore,  // [1]
    const char* __restrict__ ws,
    float* __restrict__ out)           // [8][256][64]  (g*16384 + e*64 + d), fp32
{
  __shared__ __align__(16) __bf16 s_ee[256*LDE];   // edge state
  __shared__ __align__(16) __bf16 s_h [64*LDE];    // node state
  __shared__ __align__(16) __bf16 s_p2[64*LDE];    // h@W2 (reused as agg)
  __shared__ __align__(16) __bf16 s_p3[64*LDE];    // h@W3 + ce
  __shared__ int s_off[65];
  __shared__ int s_eid[256];
  __shared__ float s_sc[256];

  const __bf16* wt  = (const __bf16*)(ws + WS_WT);
  const float*  xap = (const float*)(ws + WS_XAP);
  const float*  xdp = (const float*)(ws + WS_XDP);
  const __bf16* ee0 = (const __bf16*)(ws + WS_EE0);
  const float*  cev = (const float*)(ws + WS_CE);
  const float*  cnv = (const float*)(ws + WS_CN);
  const int* csroff = (const int*)(ws + WS_CSROFF);
  const int* csreid = (const int*)(ws + WS_CSREID);

  const int tid = threadIdx.x;
  const int w = tid >> 6, l = tid & 63;
  const int q = l >> 4, xn = l & 15;
  const int lane8 = l*8;                  // packed-fragment lane offset
  const int fme = w*16 + q*4;             // this wave's epilogue f-offset
  const int g = blockIdx.x >> 6, d = blockIdx.x & 63;

  if (tid < 65) s_off[tid] = csroff[g*72 + tid];
  if (tid < 256) s_eid[tid] = csreid[g*256 + tid];

  // node encoder: h[i][f] = leaky(xap[i][f] + xdp[d][f] + sp(d,i)*wsp[f])
  {
    const int f = tid & 127, ib = tid >> 7;   // ib in [0,4)
    float xdpv = xdp[(g*64 + d)*128 + f];
    float wspv = Wne[256*128 + f];
    #pragma unroll
    for (int j = 0; j < 16; ++j) {
      int i = ib + 4*j;
      float sp = spdist[(g*64 + d)*64 + i];
      float v = xap[(g*64 + i)*128 + f] + xdpv + sp*wspv;
      s_h[i*LDE + f] = (__bf16)leaky(v);
    }
  }
  // stage ee0 -> LDS (4096 chunks of 16B)
  #pragma unroll
  for (int it = 0; it < 8; ++it) {
    int c = it*512 + tid;
    int row = c >> 4, col = c & 15;
    *(bf16x8*)&s_ee[row*LDE + col*8] = *(const bf16x8*)&ee0[(g*256 + row)*128 + col*8];
  }

  // per-lane src/dst for edge e = t*16 + xn, t = 0..15
  int mySrc[16], myDst[16];
  #pragma unroll
  for (int t = 0; t < 16; ++t) {
    int e = t*16 + xn;
    mySrc[t] = eidx[g*512 + e];
    myDst[t] = eidx[g*512 + 256 + e];
  }
  __syncthreads();

  for (int s = 0; s < 2; ++s) {
    const __bf16* W1T = wt + (s*5 + 0)*16384;
    const __bf16* W2T = wt + (s*5 + 1)*16384;
    const __bf16* W3T = wt + (s*5 + 2)*16384;
    const __bf16* N1T = wt + (s*5 + 3)*16384;
    const __bf16* N2T = wt + (s*5 + 4)*16384;

    // ---- phase 1: s_p2 = h@W2 ; s_p3 = h@W3 + ce.
    // wave w: all 64 nodes, f-range w*16..+16. Writes disjoint from reads.
    {
      bf16x8 aw2[4], aw3[4];
      #pragma unroll
      for (int c = 0; c < 4; ++c) {
        aw2[c] = *(const bf16x8*)&W2T[(w*4 + c)*512 + lane8];
        aw3[c] = *(const bf16x8*)&W3T[(w*4 + c)*512 + lane8];
      }
      floatx4 ce4 = *(const floatx4*)&cev[(g*2 + s)*128 + fme];
      #pragma unroll
      for (int t = 0; t < 4; ++t) {
        const int i = t*16 + xn;
        floatx4 a2 = (floatx4)0.f, a3 = (floatx4)0.f;
        #pragma unroll
        for (int c = 0; c < 4; ++c) {
          bf16x8 bh = *(const bf16x8*)&s_h[i*LDE + c*32 + q*8];
          a2 = MFMA16(aw2[c], bh, a2);
          a3 = MFMA16(aw3[c], bh, a3);
        }
        bf16x4 o2, o3;
        #pragma unroll
        for (int r = 0; r < 4; ++r) { o2[r] = (__bf16)a2[r]; o3[r] = (__bf16)(a3[r] + ce4[r]); }
        *(bf16x4*)&s_p2[i*LDE + fme] = o2;
        *(bf16x4*)&s_p3[i*LDE + fme] = o3;
      }
    }
    __syncthreads();

    // ---- phase 2: ee += leaky(ee@W1 + p2[src] + p3[dst]).
    // wave w: all 256 edges, f-range w*16..+16. Compute accs (reads) ->
    // barrier -> epilogue writes (wave-exclusive 8-B chunks).
    {
      bf16x8 aw1[4];
      #pragma unroll
      for (int c = 0; c < 4; ++c)
        aw1[c] = *(const bf16x8*)&W1T[(w*4 + c)*512 + lane8];
      floatx4 acc[16];
      #pragma unroll
      for (int t = 0; t < 16; ++t) {
        const int e = t*16 + xn;
        floatx4 a = (floatx4)0.f;
        #pragma unroll
        for (int c = 0; c < 4; ++c) {
          bf16x8 be = *(const bf16x8*)&s_ee[e*LDE + c*32 + q*8];
          a = MFMA16(aw1[c], be, a);
        }
        acc[t] = a;
      }
      __syncthreads();   // all k-reads of s_ee complete before any f-slice write
      #pragma unroll
      for (int t = 0; t < 16; ++t) {
        const int e = t*16 + xn;
        bf16x4 old = *(const bf16x4*)&s_ee[e*LDE + fme];
        bf16x4 v2  = *(const bf16x4*)&s_p2[mySrc[t]*LDE + fme];
        bf16x4 v3  = *(const bf16x4*)&s_p3[myDst[t]*LDE + fme];
        bf16x4 res;
        #pragma unroll
        for (int r = 0; r < 4; ++r) {
          float vv = acc[t][r] + (float)v2[r] + (float)v3[r];
          res[r] = (__bf16)((float)old[r] + leaky(vv));
        }
        *(bf16x4*)&s_ee[e*LDE + fme] = res;
      }
    }
    __syncthreads();

    if (s == 0) {  // last step's node update is unused -> skip
      // ---- phase 3: agg = segment_sum(ee, dst) -> s_p2 (bf16). 8 thr/node.
      {
        const int node = tid >> 3;
        const int fs = (tid & 7)*16;
        float av[16];
        #pragma unroll
        for (int j = 0; j < 16; ++j) av[j] = 0.f;
        const int b0 = s_off[node], b1 = s_off[node + 1];
        for (int idx = b0; idx < b1; ++idx) {
          int e = s_eid[idx];
          #pragma unroll
          for (int cc = 0; cc < 2; ++cc) {
            bf16x8 vv = *(const bf16x8*)&s_ee[e*LDE + fs + cc*8];
            #pragma unroll
            for (int j = 0; j < 8; ++j) av[cc*8 + j] += (float)vv[j];
          }
        }
        #pragma unroll
        for (int cc = 0; cc < 2; ++cc) {
          bf16x8 o;
          #pragma unroll
          for (int j = 0; j < 8; ++j) o[j] = (__bf16)av[cc*8 + j];
          *(bf16x8*)&s_p2[node*LDE + fs + cc*8] = o;
        }
      }
      __syncthreads();
      // ---- phase 4: h += leaky(h@Wn1 + agg@Wn2 + cn).
      // wave w: all 64 nodes, f-range w*16..+16. Compute -> barrier -> write.
      {
        bf16x8 an1[4], an2[4];
        #pragma unroll
        for (int c = 0; c < 4; ++c) {
          an1[c] = *(const bf16x8*)&N1T[(w*4 + c)*512 + lane8];
          an2[c] = *(const bf16x8*)&N2T[(w*4 + c)*512 + lane8];
        }
        floatx4 acc4[4];
        #pragma unroll
        for (int t = 0; t < 4; ++t) {
          const int i = t*16 + xn;
          floatx4 a = (floatx4)0.f;
          #pragma unroll
          for (int c = 0; c < 4; ++c) {
            bf16x8 bh = *(const bf16x8*)&s_h[i*LDE + c*32 + q*8];
            a = MFMA16(an1[c], bh, a);
          }
          #pragma unroll
          for (int c = 0; c < 4; ++c) {
            bf16x8 bg = *(const bf16x8*)&s_p2[i*LDE + c*32 + q*8];
            a = MFMA16(an2[c], bg, a);
          }
          acc4[t] = a;
        }
        __syncthreads();   // all k-reads of s_h complete before any f-slice write
        floatx4 cn4 = *(const floatx4*)&cnv[(g*2 + s)*128 + fme];
        #pragma unroll
        for (int t = 0; t < 4; ++t) {
          const int i = t*16 + xn;
          bf16x4 old = *(const bf16x4*)&s_h[i*LDE + fme];
          bf16x4 res;
          #pragma unroll
          for (int r = 0; r < 4; ++r)
            res[r] = (__bf16)((float)old[r] + leaky(acc4[t][r] + cn4[r]));
          *(bf16x4*)&s_h[i*LDE + fme] = res;
        }
      }
      __syncthreads();
    }
  }

  // ---- scores: out[g, e, d] = ee[e] . wscore + b  (fp32 output)
  {
    const int e = tid & 255, hh = tid >> 8;
    float acc = 0.f;
    #pragma unroll
    for (int c = 0; c < 8; ++c) {
      bf16x8 vv = *(const bf16x8*)&s_ee[e*LDE + hh*64 + c*8];
      #pragma unroll
      for (int j = 0; j < 8; ++j) acc += (float)vv[j] * wscore[hh*64 + c*8 + j];
    }
    if (hh == 1) s_sc[e] = acc;
    __syncthreads();
    if (hh == 0) out[g*16384 + e*64 + d] = acc + s_sc[e] + bscore[0];
  }
}

extern "C" void kernel_launch(void* const* d_in, const int* in_sizes, int n_in,
                              void* d_out, int out_size, void* d_ws, size_t ws_size,
                              hipStream_t stream) {
  (void)in_sizes; (void)n_in; (void)out_size; (void)ws_size;
  const float* x   = (const float*)d_in[0];
  const float* ea  = (const float*)d_in[1];
  const float* u   = (const float*)d_in[2];
  const float* sp  = (const float*)d_in[3];
  const int*   ei  = (const int*)d_in[4];
  const float* Wne = (const float*)d_in[5];
  const float* bne = (const float*)d_in[6];
  const float* Wee = (const float*)d_in[7];
  const float* bee = (const float*)d_in[8];
  const float* Wge = (const float*)d_in[9];
  const float* bge = (const float*)d_in[10];
  const float* Weu = (const float*)d_in[11];
  const float* beu = (const float*)d_in[12];
  const float* Wnu = (const float*)d_in[13];
  const float* bnu = (const float*)d_in[14];
  const float* Wsc = (const float*)d_in[15];
  const float* bsc = (const float*)d_in[16];
  char* ws = (char*)d_ws;

  hipLaunchKernelGGL(mpn_prep, dim3(44), dim3(256), 0, stream,
                     x, ea, u, ei, Wne, bne, Wee, bee, Wge, bge, Weu, beu, Wnu, bnu, ws);
  hipLaunchKernelGGL(mpn_main, dim3(512), dim3(512), 0, stream,
                     sp, ei, Wne, Wsc, bsc, (const char*)ws, (float*)d_out);
}

// Round 10
// 153.223 us; speedup vs baseline: 1.2798x; 1.0331x over previous
//
#include <hip/hip_runtime.h>
#include <hip/hip_bf16.h>

// MPNScoreModule: B=8 graphs, N=64 nodes, E=256 edges, L=128, S=2 steps.
// Round 10: hybrid of rounds 8/9 (both correctness-verified):
//  - phase 2 (edge GEMM): round-8 mapping -- wave-pair owns 64 edges, B-frags
//    reused across 4 MFMAs each (round-9's m=w mapping quadrupled LDS reads
//    and regressed 48.5->60us; FETCH_SIZE identical proved L2 wasn't the cost).
//  - phases 1/4 (node GEMMs): round-9 mapping (m=w) -- 4 weight frags/matrix
//    per wave, prefetchable.
//  - NEW: step-start register prefetch of all weight fragments (W2,W3,N1,N2:
//    4 each; W1: 16) so no phase opens with a cold L2 load behind a barrier.

typedef __attribute__((ext_vector_type(8))) __bf16 bf16x8;
typedef __attribute__((ext_vector_type(4))) __bf16 bf16x4;
typedef __attribute__((ext_vector_type(4))) float  floatx4;

#define MFMA16(a, b, c) __builtin_amdgcn_mfma_f32_16x16x32_bf16((a), (b), (c), 0, 0, 0)

__device__ __forceinline__ float leaky(float x) { return x > 0.f ? x : 0.01f * x; }

// ---- workspace layout (bytes) ----
#define WS_WT     0          // bf16 [10][16384] PACKED weights: [m][(mq*4+c)*64+l][8]
#define WS_XAP    327680     // f32  [8][64][128]  x @ Wne[0:128] + b_node_enc
#define WS_XDP    589824     // f32  [8][64][128]  x @ Wne[128:256]
#define WS_EE0    851968     // bf16 [8][256][128] leaky(edge_attr @ Wee + b)
#define WS_CE     1376256    // f32  [8][2][128]   gg @ W4  + b_edge_upd
#define WS_CN     1384448    // f32  [8][2][128]   gg @ Wn3 + b_node_upd
#define WS_CSROFF 1392640    // int  [8][72]
#define WS_CSREID 1394944    // int  [8][256]
// end ~1.4 MB

#define LDE 140   // padded LDS row stride: 280 B = 70 dw = 6 mod 32 -> conflict-free

// ============================ prep kernel (round 8, unchanged) ============================
__global__ __launch_bounds__(256) void mpn_prep(
    const float* __restrict__ x,     // [8][64][128]
    const float* __restrict__ ea,    // [8][256][128]
    const float* __restrict__ u,     // [8][128]
    const int*   __restrict__ eidx,  // [8][2][256]
    const float* __restrict__ Wne,   // [257][128]
    const float* __restrict__ bne,   // [128]
    const float* __restrict__ Wee,   // [128][128]
    const float* __restrict__ bee,   // [128]
    const float* __restrict__ Wge,   // [128][128]
    const float* __restrict__ bge,   // [128]
    const float* __restrict__ Weu,   // [2][512][128]
    const float* __restrict__ beu,   // [2][128]
    const float* __restrict__ Wnu,   // [2][384][128]
    const float* __restrict__ bnu,   // [2][128]
    char* __restrict__ ws)
{
  __shared__ __align__(16) __bf16 smem[384 * LDE];

  const int b = blockIdx.x, tid = threadIdx.x;
  __bf16* wt  = (__bf16*)(ws + WS_WT);
  float*  xap = (float*)(ws + WS_XAP);
  float*  xdp = (float*)(ws + WS_XDP);
  __bf16* ee0 = (__bf16*)(ws + WS_EE0);
  float*  cev = (float*)(ws + WS_CE);
  float*  cnv = (float*)(ws + WS_CN);
  int* csroff = (int*)(ws + WS_CSROFF);
  int* csreid = (int*)(ws + WS_CSREID);

  if (b < 20) {
    // pack the 10 [128][128] weight blocks into wave-load order:
    // wt[m*16384 + ((mq*4+c)*64 + l)*8 + j] = src[(c*32 + (l>>4)*8 + j)*128 + mq*16 + (l&15)]
    const int m = b >> 1, half = b & 1;
    const int s = m / 5, t = m % 5;
    const float* src = (t < 3) ? (Weu + (size_t)(s*512 + t*128)*128)
                               : (Wnu + (size_t)(s*384 + (t-3)*128)*128);
    for (int it = 0; it < 4; ++it) {
      int p = it*256 + tid;
      int mq = half*4 + (p >> 8);
      int c  = (p >> 6) & 3;
      int l  = p & 63;
      int fr = mq*16 + (l & 15);
      int kb = c*32 + (l >> 4)*8;
      __bf16* dst = &wt[m*16384 + ((mq*4 + c)*64 + l)*8];
      #pragma unroll
      for (int j = 0; j < 8; ++j)
        dst[j] = (__bf16)src[(kb + j)*128 + fr];
    }
  } else if (b < 28) {
    const int g = b - 20;
    __shared__ float gg_sh[128];
    __shared__ int dst_sh[256];
    __shared__ int cnt_sh[64];
    __shared__ int off_sh[65];
    if (tid < 128) {
      float acc = bge[tid];
      for (int k = 0; k < 128; ++k)
        acc += u[g*128 + k] * Wge[k*128 + tid];
      gg_sh[tid] = leaky(acc);
    }
    dst_sh[tid] = eidx[g*512 + 256 + tid];
    __syncthreads();
    {
      const int s = tid >> 7, f = tid & 127;
      float ac = beu[s*128 + f];
      float an = bnu[s*128 + f];
      #pragma unroll 8
      for (int k = 0; k < 128; ++k) {
        float gk = gg_sh[k];
        ac += gk * Weu[(s*512 + 384 + k)*128 + f];
        an += gk * Wnu[(s*384 + 256 + k)*128 + f];
      }
      cev[(g*2 + s)*128 + f] = ac;
      cnv[(g*2 + s)*128 + f] = an;
    }
    if (tid < 64) {
      int c = 0;
      for (int e = 0; e < 256; ++e) c += (dst_sh[e] == tid) ? 1 : 0;
      cnt_sh[tid] = c;
    }
    __syncthreads();
    if (tid == 0) {
      int o = 0;
      for (int n = 0; n < 64; ++n) { off_sh[n] = o; o += cnt_sh[n]; }
      off_sh[64] = o;
    }
    __syncthreads();
    if (tid < 65) csroff[g*72 + tid] = off_sh[tid];
    if (tid < 64) {
      int o = off_sh[tid];
      for (int e = 0; e < 256; ++e)
        if (dst_sh[e] == tid) csreid[g*256 + (o++)] = e;
    }
  } else if (b < 36) {
    // ee0 = leaky(edge_attr @ Wee + bee) via MFMA, one block per graph
    const int g = b - 28;
    __bf16* s_a = smem;
    __bf16* s_w = smem + 256*LDE;
    #pragma unroll
    for (int it = 0; it < 32; ++it) {
      int c = it*256 + tid;
      int row = c >> 5, f4 = (c & 31)*4;
      floatx4 v = *(const floatx4*)&ea[(size_t)(g*256 + row)*128 + f4];
      bf16x4 o;
      #pragma unroll
      for (int r = 0; r < 4; ++r) o[r] = (__bf16)v[r];
      *(bf16x4*)&s_a[row*LDE + f4] = o;
    }
    #pragma unroll 8
    for (int it = 0; it < 64; ++it) {
      int k = it*2 + (tid >> 7), f = tid & 127;
      s_w[f*LDE + k] = (__bf16)Wee[k*128 + f];
    }
    __syncthreads();
    const int w = tid >> 6, l = tid & 63, q = l >> 4, xn = l & 15;
    bf16x8 bea[4][4];
    #pragma unroll
    for (int t = 0; t < 4; ++t) {
      int e = w*64 + t*16 + xn;
      #pragma unroll
      for (int c = 0; c < 4; ++c)
        bea[t][c] = *(const bf16x8*)&s_a[e*LDE + c*32 + q*8];
    }
    #pragma unroll
    for (int m = 0; m < 8; ++m) {
      floatx4 acc[4];
      #pragma unroll
      for (int t = 0; t < 4; ++t) acc[t] = (floatx4)0.f;
      const int fr = m*16 + xn;
      #pragma unroll
      for (int c = 0; c < 4; ++c) {
        bf16x8 aw = *(const bf16x8*)&s_w[fr*LDE + c*32 + q*8];
        #pragma unroll
        for (int t = 0; t < 4; ++t) acc[t] = MFMA16(aw, bea[t][c], acc[t]);
      }
      const int f0 = m*16 + q*4;
      floatx4 b4 = *(const floatx4*)&bee[f0];
      #pragma unroll
      for (int t = 0; t < 4; ++t) {
        int e = w*64 + t*16 + xn;
        bf16x4 o;
        #pragma unroll
        for (int r = 0; r < 4; ++r) o[r] = (__bf16)leaky(acc[t][r] + b4[r]);
        *(bf16x4*)&ee0[(size_t)(g*256 + e)*128 + f0] = o;
      }
    }
  } else {
    // xap = x @ Wne[0:128] + bne ; xdp = x @ Wne[128:256]  via MFMA, per graph
    const int g = b - 36;
    __bf16* s_x  = smem;
    __bf16* s_wa = smem + 64*LDE;
    __bf16* s_wb = smem + 192*LDE;
    #pragma unroll
    for (int it = 0; it < 8; ++it) {
      int c = it*256 + tid;
      int row = c >> 5, f4 = (c & 31)*4;
      floatx4 v = *(const floatx4*)&x[(size_t)(g*64 + row)*128 + f4];
      bf16x4 o;
      #pragma unroll
      for (int r = 0; r < 4; ++r) o[r] = (__bf16)v[r];
      *(bf16x4*)&s_x[row*LDE + f4] = o;
    }
    #pragma unroll 8
    for (int it = 0; it < 64; ++it) {
      int k = it*2 + (tid >> 7), f = tid & 127;
      s_wa[f*LDE + k] = (__bf16)Wne[k*128 + f];
      s_wb[f*LDE + k] = (__bf16)Wne[(128 + k)*128 + f];
    }
    __syncthreads();
    const int w = tid >> 6, l = tid & 63, q = l >> 4, xn = l & 15;
    const int i = w*16 + xn;
    bf16x8 bx[4];
    #pragma unroll
    for (int c = 0; c < 4; ++c)
      bx[c] = *(const bf16x8*)&s_x[i*LDE + c*32 + q*8];
    #pragma unroll
    for (int m = 0; m < 8; ++m) {
      floatx4 aa = (floatx4)0.f, ab = (floatx4)0.f;
      const int fr = m*16 + xn;
      #pragma unroll
      for (int c = 0; c < 4; ++c) {
        bf16x8 aw = *(const bf16x8*)&s_wa[fr*LDE + c*32 + q*8];
        aa = MFMA16(aw, bx[c], aa);
      }
      #pragma unroll
      for (int c = 0; c < 4; ++c) {
        bf16x8 aw = *(const bf16x8*)&s_wb[fr*LDE + c*32 + q*8];
        ab = MFMA16(aw, bx[c], ab);
      }
      const int f0 = m*16 + q*4;
      floatx4 bn4 = *(const floatx4*)&bne[f0];
      floatx4 oa;
      #pragma unroll
      for (int r = 0; r < 4; ++r) oa[r] = aa[r] + bn4[r];
      *(floatx4*)&xap[(size_t)(g*64 + i)*128 + f0] = oa;
      *(floatx4*)&xdp[(size_t)(g*64 + i)*128 + f0] = ab;
    }
  }
}

// ============================ main kernel ============================
// 512 threads = 8 waves. Phases 1/4: wave w owns f-slice m=w for all rows
// (4 weight frags/matrix in registers, prefetched at step start).
// Phase 2: wave-pair wp owns edges wp*64..+63, mh = w&1 splits m (B-frags
// reused 4x); its 16 W1 frags also prefetched at step start.
__global__ __launch_bounds__(512, 2) void mpn_main(
    const float* __restrict__ spdist,  // [8][64][64]
    const int*   __restrict__ eidx,    // [8][2][256]
    const float* __restrict__ Wne,     // row 256 = spdist weight
    const float* __restrict__ wscore,  // [128]
    const float* __restrict__ bscore,  // [1]
    const char* __restrict__ ws,
    float* __restrict__ out)           // [8][256][64]  (g*16384 + e*64 + d), fp32
{
  __shared__ __align__(16) __bf16 s_ee[256*LDE];   // edge state
  __shared__ __align__(16) __bf16 s_h [64*LDE];    // node state
  __shared__ __align__(16) __bf16 s_p2[64*LDE];    // h@W2 (reused as agg)
  __shared__ __align__(16) __bf16 s_p3[64*LDE];    // h@W3 + ce
  __shared__ int s_off[65];
  __shared__ int s_eid[256];
  __shared__ float s_sc[256];

  const __bf16* wt  = (const __bf16*)(ws + WS_WT);
  const float*  xap = (const float*)(ws + WS_XAP);
  const float*  xdp = (const float*)(ws + WS_XDP);
  const __bf16* ee0 = (const __bf16*)(ws + WS_EE0);
  const float*  cev = (const float*)(ws + WS_CE);
  const float*  cnv = (const float*)(ws + WS_CN);
  const int* csroff = (const int*)(ws + WS_CSROFF);
  const int* csreid = (const int*)(ws + WS_CSREID);

  const int tid = threadIdx.x;
  const int w = tid >> 6, l = tid & 63;
  const int q = l >> 4, xn = l & 15;
  const int wp = w >> 1, mh = w & 1;      // phase-2 wave pair / m-half
  const int lane8 = l*8;                  // packed-fragment lane offset
  const int fme = w*16 + q*4;             // phase-1/4 epilogue f-offset
  const int g = blockIdx.x >> 6, d = blockIdx.x & 63;

  if (tid < 65) s_off[tid] = csroff[g*72 + tid];
  if (tid < 256) s_eid[tid] = csreid[g*256 + tid];

  // node encoder: h[i][f] = leaky(xap[i][f] + xdp[d][f] + sp(d,i)*wsp[f])
  {
    const int f = tid & 127, ib = tid >> 7;   // ib in [0,4)
    float xdpv = xdp[(g*64 + d)*128 + f];
    float wspv = Wne[256*128 + f];
    #pragma unroll
    for (int j = 0; j < 16; ++j) {
      int i = ib + 4*j;
      float sp = spdist[(g*64 + d)*64 + i];
      float v = xap[(g*64 + i)*128 + f] + xdpv + sp*wspv;
      s_h[i*LDE + f] = (__bf16)leaky(v);
    }
  }
  // stage ee0 -> LDS (4096 chunks of 16B)
  #pragma unroll
  for (int it = 0; it < 8; ++it) {
    int c = it*512 + tid;
    int row = c >> 4, col = c & 15;
    *(bf16x8*)&s_ee[row*LDE + col*8] = *(const bf16x8*)&ee0[(g*256 + row)*128 + col*8];
  }

  // phase-2 per-lane src/dst (round-8 mapping: e = wp*64 + t*16 + xn)
  int mySrc[4], myDst[4];
  #pragma unroll
  for (int t = 0; t < 4; ++t) {
    int e = wp*64 + t*16 + xn;
    mySrc[t] = eidx[g*512 + e];
    myDst[t] = eidx[g*512 + 256 + e];
  }
  __syncthreads();

  for (int s = 0; s < 2; ++s) {
    const __bf16* W1T = wt + (s*5 + 0)*16384;
    const __bf16* W2T = wt + (s*5 + 1)*16384;
    const __bf16* W3T = wt + (s*5 + 2)*16384;
    const __bf16* N1T = wt + (s*5 + 3)*16384;
    const __bf16* N2T = wt + (s*5 + 4)*16384;

    // ---- step-start weight prefetch (all L2 loads issued before any compute)
    bf16x8 w2f[4], w3f[4], n1f[4], n2f[4], w1f[4][4];
    #pragma unroll
    for (int c = 0; c < 4; ++c) {
      w2f[c] = *(const bf16x8*)&W2T[(w*4 + c)*512 + lane8];
      w3f[c] = *(const bf16x8*)&W3T[(w*4 + c)*512 + lane8];
    }
    #pragma unroll
    for (int mm = 0; mm < 4; ++mm)
      #pragma unroll
      for (int c = 0; c < 4; ++c)
        w1f[mm][c] = *(const bf16x8*)&W1T[((mh*4 + mm)*4 + c)*512 + lane8];
    if (s == 0) {
      #pragma unroll
      for (int c = 0; c < 4; ++c) {
        n1f[c] = *(const bf16x8*)&N1T[(w*4 + c)*512 + lane8];
        n2f[c] = *(const bf16x8*)&N2T[(w*4 + c)*512 + lane8];
      }
    }

    // ---- phase 1: s_p2 = h@W2 ; s_p3 = h@W3 + ce  (wave w: all nodes, f-slice fme)
    {
      floatx4 ce4 = *(const floatx4*)&cev[(g*2 + s)*128 + fme];
      #pragma unroll
      for (int t = 0; t < 4; ++t) {
        const int i = t*16 + xn;
        floatx4 a2 = (floatx4)0.f, a3 = (floatx4)0.f;
        #pragma unroll
        for (int c = 0; c < 4; ++c) {
          bf16x8 bh = *(const bf16x8*)&s_h[i*LDE + c*32 + q*8];
          a2 = MFMA16(w2f[c], bh, a2);
          a3 = MFMA16(w3f[c], bh, a3);
        }
        bf16x4 o2, o3;
        #pragma unroll
        for (int r = 0; r < 4; ++r) { o2[r] = (__bf16)a2[r]; o3[r] = (__bf16)(a3[r] + ce4[r]); }
        *(bf16x4*)&s_p2[i*LDE + fme] = o2;
        *(bf16x4*)&s_p3[i*LDE + fme] = o3;
      }
    }
    __syncthreads();

    // ---- phase 2: ee += leaky(ee@W1 + p2[src] + p3[dst])  (round-8 mapping)
    {
      bf16x8 be[4][4];
      #pragma unroll
      for (int t = 0; t < 4; ++t) {
        int e = wp*64 + t*16 + xn;
        #pragma unroll
        for (int c = 0; c < 4; ++c)
          be[t][c] = *(const bf16x8*)&s_ee[e*LDE + c*32 + q*8];
      }
      __syncthreads();   // snapshot complete before any pair-member writes
      #pragma unroll
      for (int mm = 0; mm < 4; ++mm) {
        const int m = mh*4 + mm;
        floatx4 acc[4];
        #pragma unroll
        for (int t = 0; t < 4; ++t) acc[t] = (floatx4)0.f;
        #pragma unroll
        for (int c = 0; c < 4; ++c) {
          #pragma unroll
          for (int t = 0; t < 4; ++t) acc[t] = MFMA16(w1f[mm][c], be[t][c], acc[t]);
        }
        const int f0 = m*16 + q*4;
        #pragma unroll
        for (int t = 0; t < 4; ++t) {
          int e = wp*64 + t*16 + xn;
          bf16x4 old = *(const bf16x4*)&s_ee[e*LDE + f0];
          bf16x4 v2  = *(const bf16x4*)&s_p2[mySrc[t]*LDE + f0];
          bf16x4 v3  = *(const bf16x4*)&s_p3[myDst[t]*LDE + f0];
          bf16x4 res;
          #pragma unroll
          for (int r = 0; r < 4; ++r) {
            float vv = acc[t][r] + (float)v2[r] + (float)v3[r];
            res[r] = (__bf16)((float)old[r] + leaky(vv));
          }
          *(bf16x4*)&s_ee[e*LDE + f0] = res;
        }
      }
    }
    __syncthreads();

    if (s == 0) {  // last step's node update is unused -> skip
      // ---- phase 3: agg = segment_sum(ee, dst) -> s_p2 (bf16). 8 thr/node.
      {
        const int node = tid >> 3;
        const int fs = (tid & 7)*16;
        float av[16];
        #pragma unroll
        for (int j = 0; j < 16; ++j) av[j] = 0.f;
        const int b0 = s_off[node], b1 = s_off[node + 1];
        for (int idx = b0; idx < b1; ++idx) {
          int e = s_eid[idx];
          #pragma unroll
          for (int cc = 0; cc < 2; ++cc) {
            bf16x8 vv = *(const bf16x8*)&s_ee[e*LDE + fs + cc*8];
            #pragma unroll
            for (int j = 0; j < 8; ++j) av[cc*8 + j] += (float)vv[j];
          }
        }
        #pragma unroll
        for (int cc = 0; cc < 2; ++cc) {
          bf16x8 o;
          #pragma unroll
          for (int j = 0; j < 8; ++j) o[j] = (__bf16)av[cc*8 + j];
          *(bf16x8*)&s_p2[node*LDE + fs + cc*8] = o;
        }
      }
      __syncthreads();
      // ---- phase 4: h += leaky(h@Wn1 + agg@Wn2 + cn)  (wave w: all nodes, f-slice fme)
      {
        floatx4 acc4[4];
        #pragma unroll
        for (int t = 0; t < 4; ++t) {
          const int i = t*16 + xn;
          floatx4 a = (floatx4)0.f;
          #pragma unroll
          for (int c = 0; c < 4; ++c) {
            bf16x8 bh = *(const bf16x8*)&s_h[i*LDE + c*32 + q*8];
            a = MFMA16(n1f[c], bh, a);
          }
          #pragma unroll
          for (int c = 0; c < 4; ++c) {
            bf16x8 bg = *(const bf16x8*)&s_p2[i*LDE + c*32 + q*8];
            a = MFMA16(n2f[c], bg, a);
          }
          acc4[t] = a;
        }
        __syncthreads();   // all k-reads of s_h complete before any f-slice write
        floatx4 cn4 = *(const floatx4*)&cnv[(g*2 + s)*128 + fme];
        #pragma unroll
        for (int t = 0; t < 4; ++t) {
          const int i = t*16 + xn;
          bf16x4 old = *(const bf16x4*)&s_h[i*LDE + fme];
          bf16x4 res;
          #pragma unroll
          for (int r = 0; r < 4; ++r)
            res[r] = (__bf16)((float)old[r] + leaky(acc4[t][r] + cn4[r]));
          *(bf16x4*)&s_h[i*LDE + fme] = res;
        }
      }
      __syncthreads();
    }
  }

  // ---- scores: out[g, e, d] = ee[e] . wscore + b  (fp32 output)
  {
    const int e = tid & 255, hh = tid >> 8;
    float acc = 0.f;
    #pragma unroll
    for (int c = 0; c < 8; ++c) {
      bf16x8 vv = *(const bf16x8*)&s_ee[e*LDE + hh*64 + c*8];
      #pragma unroll
      for (int j = 0; j < 8; ++j) acc += (float)vv[j] * wscore[hh*64 + c*8 + j];
    }
    if (hh == 1) s_sc[e] = acc;
    __syncthreads();
    if (hh == 0) out[g*16384 + e*64 + d] = acc + s_sc[e] + bscore[0];
  }
}

extern "C" void kernel_launch(void* const* d_in, const int* in_sizes, int n_in,
                              void* d_out, int out_size, void* d_ws, size_t ws_size,
                              hipStream_t stream) {
  (void)in_sizes; (void)n_in; (void)out_size; (void)ws_size;
  const float* x   = (const float*)d_in[0];
  const float* ea  = (const float*)d_in[1];
  const float* u   = (const float*)d_in[2];
  const float* sp  = (const float*)d_in[3];
  const int*   ei  = (const int*)d_in[4];
  const float* Wne = (const float*)d_in[5];
  const float* bne = (const float*)d_in[6];
  const float* Wee = (const float*)d_in[7];
  const float* bee = (const float*)d_in[8];
  const float* Wge = (const float*)d_in[9];
  const float* bge = (const float*)d_in[10];
  const float* Weu = (const float*)d_in[11];
  const float* beu = (const float*)d_in[12];
  const float* Wnu = (const float*)d_in[13];
  const float* bnu = (const float*)d_in[14];
  const float* Wsc = (const float*)d_in[15];
  const float* bsc = (const float*)d_in[16];
  char* ws = (char*)d_ws;

  hipLaunchKernelGGL(mpn_prep, dim3(44), dim3(256), 0, stream,
                     x, ea, u, ei, Wne, bne, Wee, bee, Wge, bge, Weu, beu, Wnu, bnu, ws);
  hipLaunchKernelGGL(mpn_main, dim3(512), dim3(512), 0, stream,
                     sp, ei, Wne, Wsc, bsc, (const char*)ws, (float*)d_out);
}